// Round 6
// baseline (504.843 us; speedup 1.0000x reference)
//
#include <hip/hip_runtime.h>
#include <math.h>
#include <limits.h>

#define S_N 65536
#define D_N 512
#define B_N 64

typedef __attribute__((ext_vector_type(8))) short short8;
typedef __attribute__((ext_vector_type(4))) float f32x4;

// ---------------- workspace layout (float indices) ----------------
#define SIMS_F      (B_N*S_N/2)                 // bf16 sims stored as ushort
#define OFF_SIMS    0
#define OFF_AEXT    (OFF_SIMS + SIMS_F)         // ushort[96*512]: rows 0..63 norm(nc), 64..95 ec_w^T (bf16)
#define AEXT_F      (96*512/2)
#define OFF_NORMS   (OFF_AEXT + AEXT_F)
#define OFF_CONF    (OFF_NORMS + S_N)
#define OFF_FLAGS   (OFF_CONF + S_N)            // int
#define OFF_LIST    (OFF_FLAGS + S_N)           // int[256] touched rows
#define OFF_MASKED  (OFF_LIST + 256)
#define OFF_ERSC    (OFF_MASKED + S_N)
#define OFF_SLOTAGE (OFF_ERSC + S_N)
#define OFF_STORES  (OFF_SLOTAGE + S_N)         // 64
#define OFF_MAXSIM  (OFF_STORES + 64)           // 64 u32 mono
#define OFF_TI      (OFF_MAXSIM + 64)           // 192 int
#define OFF_TV      (OFF_TI + 192)              // 192
#define OFF_APPLY   (OFF_TV + 192)              // 192 int
#define OFF_HM      (OFF_APPLY + 192)           // mlp1 partials: NOW [8][64][256] = 131072 floats,
                                                //   spills into HNC+HG space (safe: initm writes, k_mid
                                                //   reads, only then k_mlp2 overwrites HNC/HG)
#define OFF_HNC     (OFF_HM + 32768)            // 2*64*2*256 mlp2 nc-half partials
#define OFF_HG      (OFF_HNC + 65536)           // 2*192*2*256 mlp2 gathered-half partials
#define OFF_DNC0    (OFF_HG + 196608)           // 3*512
#define OFF_DRIFT0  (OFF_DNC0 + 1536)           // 512
#define OFF_DOCAND  (OFF_DRIFT0 + 512)          // 192*512
#define OFF_SNP     OFF_DOCAND                  // [4][64][2][128]=65536 nf partials (initm writes,
                                                //   mlp1b reads, only then pairfin overwrites DOCAND)
#define OFF_SCAL    (OFF_DOCAND + 98304)

// ---------------- output layout (floats) ----------------
#define OUT_MEM 0
#define OUT_AT  (S_N*D_N)
#define OUT_ER  (OUT_AT + S_N)
#define OUT_SS  (OUT_ER + S_N)
#define OUT_NOV (OUT_SS + 64)
#define OUT_RC  (OUT_NOV + 64)

struct __align__(8) Scal {
  unsigned long long victim_pack;
  unsigned long long masked_pack;
  unsigned long long slotage_pack;
  int cnt_active;
  int cond_cnt;
  unsigned age_max_t;
  float nov_mean;
  float changed_sum;
  int do_erase;
  int should_store;
  int write_idx;
  int victim_idx;
  int list_cnt;
};

__device__ __forceinline__ float sigmoidf_(float x){ return 1.0f/(1.0f+expf(-x)); }
__device__ __forceinline__ unsigned f2mono(float f){
  unsigned u = __float_as_uint(f);
  return (u & 0x80000000u) ? ~u : (u | 0x80000000u);
}
__device__ __forceinline__ float mono2f(unsigned m){
  unsigned u = (m & 0x80000000u) ? (m & 0x7FFFFFFFu) : ~m;
  return __uint_as_float(u);
}
__device__ __forceinline__ unsigned long long packvi(float v, int i){
  return (((unsigned long long)f2mono(v)) << 32) | (unsigned long long)(0xFFFFFFFFu - (unsigned)i);
}
__device__ __forceinline__ bool betterVI(float v, int i, float v2, int i2){
  return (v > v2) || (v == v2 && i < i2);
}
__device__ __forceinline__ unsigned short bf16r(float f){   // RNE f32->bf16
  unsigned u = __float_as_uint(f);
  return (unsigned short)((u + 0x7fffu + ((u>>16)&1u)) >> 16);
}
__device__ __forceinline__ float bf2f(unsigned short h){
  return __uint_as_float(((unsigned)h)<<16);
}
__device__ __forceinline__ void touch_row(int row, float* ws){
  int* flags = (int*)(ws + OFF_FLAGS);
  if (atomicExch(&flags[row], 1) == 0){
    Scal* sc = (Scal*)(ws + OFF_SCAL);
    int i = atomicAdd(&sc->list_cnt, 1);
    ((int*)(ws + OFF_LIST))[i] = row;
  }
}

// async global->LDS, 16B per lane. dest = wave-uniform base + lane*16; src per-lane.
__device__ __forceinline__ void gld16(const float* g, void* l){
  __builtin_amdgcn_global_load_lds((const __attribute__((address_space(1))) void*)g,
                                   (__attribute__((address_space(3))) void*)l, 16, 0, 0);
}
#define WAITV(N) asm volatile("s_waitcnt vmcnt(" #N ")" ::: "memory")

// ================= k_initm: init (289) + mlp1a ksplit8 (512) + nf partials (256) =================
__global__ __launch_bounds__(256) void k_initm(const float* __restrict__ nc,
                                               const float* __restrict__ qr,
                                               const float* __restrict__ at_in,
                                               const float* __restrict__ ec_w,
                                               const int* __restrict__ step_p,
                                               const float* __restrict__ sr_w1,
                                               const float* __restrict__ sn_w,
                                               float* __restrict__ ws, float* __restrict__ out){
  int blk = blockIdx.x, t = threadIdx.x;
  Scal* sc = (Scal*)(ws + OFF_SCAL);
  unsigned short* aB = (unsigned short*)(ws + OFF_AEXT);
  __shared__ float red[256];
  __shared__ float ch[256];
  if (blk == 0){
    if (t == 0){
      sc->victim_pack = 0ULL; sc->masked_pack = 0ULL; sc->slotage_pack = 0ULL;
      sc->cnt_active = 0; sc->cond_cnt = 0; sc->age_max_t = 0u;
      sc->nov_mean = 0.0f; sc->changed_sum = 0.0f;
      sc->do_erase = 0; sc->should_store = 0; sc->write_idx = 0; sc->victim_idx = 0;
      sc->list_cnt = 0;
      out[OUT_RC] = 0.0f;           // k_diff atomicAdds into this
    }
    if (t < 64) ((unsigned*)(ws + OFF_MAXSIM))[t] = 0u;
  } else if (blk <= 64){
    int b = blk - 1;
    float x0 = nc[b*512 + t], x1 = nc[b*512 + 256 + t];
    red[t] = x0*x0 + x1*x1;
    __syncthreads();
    for (int o=128;o>0;o>>=1){ if (t<o) red[t]+=red[t+o]; __syncthreads(); }
    float inv = 1.0f / fmaxf(sqrtf(red[0]), 1e-12f);
    aB[b*512 + t]       = bf16r(x0*inv);
    aB[b*512 + 256 + t] = bf16r(x1*inv);
  } else if (blk <= 96){
    int j = blk - 65;
    for (int d=t; d<512; d+=256) aB[(64+j)*512 + d] = bf16r(ec_w[d*32 + j]);
  } else if (blk <= 160){
    int part = blk - 97;
    float stepf = (float)step_p[0];
    float lmaxv = -1e30f;
    for (int s = part*1024 + t; s < (part+1)*1024; s += 256)
      lmaxv = fmaxf(lmaxv, fmaxf(stepf - at_in[s], 0.0f));
    red[t]=lmaxv; __syncthreads();
    for (int o=128;o>0;o>>=1){ if (t<o) red[t]=fmaxf(red[t],red[t+o]); __syncthreads(); }
    if (t==0) atomicMax(&sc->age_max_t, f2mono(red[0]));
  } else if (blk <= 224){
    int part = blk - 161;
    for (int s = part*1024 + t; s < (part+1)*1024; s += 256)
      out[OUT_AT + s] = at_in[s];
  } else if (blk <= 288){
    int part = blk - 225;   // 64 parts
    int* flags = (int*)(ws + OFF_FLAGS);
    for (int s = part*1024 + t; s < (part+1)*1024; s += 256) flags[s] = 0;
  } else if (blk <= 800){
    // ---- mlp1a: h partials, k-split 8 (512 blocks, 128-iter loops) ----
    int blk2 = blk - 289;             // 0..511
    int b = blk2 >> 3, s = blk2 & 7;
    const float* src = (s < 4) ? nc : qr;
    if (t < 128) ch[t] = src[b*512 + (s & 3)*128 + t];
    __syncthreads();
    float h = 0.f;
    const float* w = sr_w1 + (s*128)*256 + t;
    #pragma unroll 8
    for (int i=0;i<128;i++) h = fmaf(ch[i], w[i*256], h);
    ws[OFF_HM + (s*64 + b)*256 + t] = h;
  } else {
    // ---- nf (sn_w) partials: [ks 0..3][b][kh 0..1][128], 64-iter loops, all 256 threads ----
    int blk2 = blk - 801;             // 0..255
    int b = blk2 >> 2, ks = blk2 & 3;
    int o = t & 127, kh = t >> 7;
    if (t < 128) ch[t] = nc[b*512 + ks*128 + t];
    __syncthreads();
    float p = 0.f;
    const float* w = sn_w + (ks*128 + kh*64)*128 + o;
    #pragma unroll 8
    for (int i=0;i<64;i++) p = fmaf(ch[kh*64 + i], w[i*128], p);
    ws[OFF_SNP + ((ks*64 + b)*2 + kh)*128 + o] = p;
  }
}

// ================= k_phase1: FROZEN — byte-identical to the R2/R5 version (99-103 us) =================
__global__ __launch_bounds__(256) void k_phase1(const float* __restrict__ mem,
                                                const float* __restrict__ ec_b,
                                                const float* __restrict__ eg_w,
                                                float* __restrict__ ws, float* __restrict__ out){
  __shared__ __align__(16) unsigned short aT[96*520];   // 99840 B, padded rows
  __shared__ __align__(16) char chunks[4*4*2048];       // 4 waves x 4 bufs x 2KB
  __shared__ unsigned lmax[64];
  int t = threadIdx.x;
  int s0 = blockIdx.x * 64;
  Scal* sc = (Scal*)(ws + OFF_SCAL);
  int lane = t & 63, wv = t >> 6;
  int quad = lane >> 4, l15 = lane & 15;
  int row = wv*16 + l15;                 // mem row this lane consumes == its sims column

  // ---- stage Aext (bf16) global ws -> padded LDS; 6144 uint4 total ----
  {
    const uint4* src = (const uint4*)(ws + OFF_AEXT);
    #pragma unroll
    for (int i=0;i<24;i++){
      int idx = i*256 + t;
      int arow = idx >> 6, c16 = idx & 63;
      uint4 v = src[idx];
      *(uint4*)((char*)aT + arow*1040 + c16*16) = v;
    }
    if (t < 64) lmax[t] = 0u;
  }
  __syncthreads();   // drains vmcnt/lgkmcnt -> clean FIFO for counted waits below

  const float* gsrc = mem + ((size_t)(s0 + row))*512 + quad*8;
  float* od = out + OUT_MEM + ((size_t)(s0 + row))*512 + quad*8;
  char* mybuf = chunks + wv*8192;
  #define STAGE(c) do{ \
    gld16(gsrc + (c)*32,     mybuf + ((c)&3)*2048); \
    gld16(gsrc + (c)*32 + 4, mybuf + ((c)&3)*2048 + 1024); \
  }while(0)

  STAGE(0); asm volatile("" ::: "memory");
  STAGE(1); asm volatile("" ::: "memory");
  STAGE(2); asm volatile("" ::: "memory");

  f32x4 acc[6];
  #pragma unroll
  for (int r=0;r<6;r++) acc[r] = (f32x4){0.f,0.f,0.f,0.f};
  float ssq = 0.f;

  #pragma unroll
  for (int c=0;c<16;c++){
    if (c < 13) STAGE(c+3);
    if      (c == 0)  WAITV(6);
    else if (c == 1)  WAITV(8);
    else if (c == 2)  WAITV(10);
    else if (c <= 12) WAITV(12);
    else if (c == 13) WAITV(10);
    else if (c == 14) WAITV(8);
    else              WAITV(6);
    __builtin_amdgcn_sched_barrier(0);
    const char* bp = mybuf + (c&3)*2048;
    float4 v0 = *(const float4*)(bp + lane*16);
    float4 v1 = *(const float4*)(bp + 1024 + lane*16);
    *(float4*)(od + c*32)     = v0;     // copy-out fused (2 stores/iter, counted above)
    *(float4*)(od + c*32 + 4) = v1;
    ssq = fmaf(v0.x,v0.x,ssq); ssq = fmaf(v0.y,v0.y,ssq);
    ssq = fmaf(v0.z,v0.z,ssq); ssq = fmaf(v0.w,v0.w,ssq);
    ssq = fmaf(v1.x,v1.x,ssq); ssq = fmaf(v1.y,v1.y,ssq);
    ssq = fmaf(v1.z,v1.z,ssq); ssq = fmaf(v1.w,v1.w,ssq);
    short8 bfrag;
    bfrag[0]=(short)bf16r(v0.x); bfrag[1]=(short)bf16r(v0.y);
    bfrag[2]=(short)bf16r(v0.z); bfrag[3]=(short)bf16r(v0.w);
    bfrag[4]=(short)bf16r(v1.x); bfrag[5]=(short)bf16r(v1.y);
    bfrag[6]=(short)bf16r(v1.z); bfrag[7]=(short)bf16r(v1.w);
    #pragma unroll
    for (int rt=0;rt<6;rt++){
      short8 afrag = *(const short8*)&aT[(rt*16 + l15)*520 + c*32 + quad*8];
      acc[rt] = __builtin_amdgcn_mfma_f32_16x16x32_bf16(afrag, bfrag, acc[rt], 0,0,0);
    }
  }
  #undef STAGE

  // ---- row norm: quads hold disjoint col-chunks of the same row ----
  ssq += __shfl_xor(ssq, 16);
  ssq += __shfl_xor(ssq, 32);
  float nrm = sqrtf(ssq);
  float lv = 1.0f / fmaxf(nrm, 1e-12f);
  if (quad == 0) ws[OFF_NORMS + s0 + row] = nrm;
  unsigned long long m = __ballot(quad==0 && nrm > 0.5f);
  if (lane == 0) atomicAdd(&sc->cnt_active, (int)__popcll(m));

  // ---- epilogue: D[a][s] col=l15(+wv*16+s0), row=quad*4+reg ----
  unsigned short* simsb = (unsigned short*)(ws + OFF_SIMS);
  #pragma unroll
  for (int rt=0;rt<4;rt++){
    #pragma unroll
    for (int r=0;r<4;r++){
      int a = rt*16 + quad*4 + r;
      float sim = acc[rt][r] * lv;
      simsb[(size_t)a*S_N + s0 + row] = bf16r(sim);
      atomicMax(&lmax[a], f2mono(sim));
    }
  }
  float cpart = 0.f;
  #pragma unroll
  for (int rt=4;rt<6;rt++){
    #pragma unroll
    for (int r=0;r<4;r++){
      int j = (rt-4)*16 + quad*4 + r;
      cpart += sigmoidf_(acc[rt][r] + ec_b[j]) * eg_w[32+j];
    }
  }
  cpart += __shfl_down(cpart, 32);
  cpart += __shfl_down(cpart, 16);
  if (lane < 16) ws[OFF_CONF + s0 + row] = cpart;
  __syncthreads();
  if (t < 64) atomicMax(((unsigned*)(ws + OFF_MAXSIM)) + t, lmax[t]);
}

// ================= k_victim: es argmax (separate kernel so phase1 codegen stays clean) =================
__global__ __launch_bounds__(256) void k_victim(const float* __restrict__ at_in,
                                                const int* __restrict__ step_p,
                                                float* __restrict__ ws){
  int t = threadIdx.x;
  Scal* sc = (Scal*)(ws + OFF_SCAL);
  float stepf = (float)step_p[0];
  float agemax = mono2f(sc->age_max_t);
  const float* norms = ws + OFF_NORMS;
  int gid = blockIdx.x*256 + t;
  int gstride = gridDim.x*256;
  unsigned long long best = 0ULL;
  for (int s = gid; s < S_N; s += gstride){
    float age = fmaxf(stepf - at_in[s], 0.0f);
    float es = age/(agemax + 1e-6f) + (1.0f - sigmoidf_(norms[s]));
    unsigned long long pk = packvi(es, s);
    if (pk > best) best = pk;
  }
  __shared__ unsigned long long redp[256];
  redp[t] = best; __syncthreads();
  for (int o=128;o>0;o>>=1){
    if (t<o && redp[t+o] > redp[t]) redp[t] = redp[t+o];
    __syncthreads();
  }
  if (t == 0) atomicMax(&sc->victim_pack, redp[0]);
}

// ================= k_mid: mlp1b(0..64) + victimfix(65) + cond-scan(66..577) + top3(578..641) =================
__global__ __launch_bounds__(256) void k_mid(const float* __restrict__ nc, const float* __restrict__ qr,
    const float* __restrict__ sr_b1, const float* __restrict__ sr_g, const float* __restrict__ sr_beta,
    const float* __restrict__ sr_w2, const float* __restrict__ sr_b2,
    const float* __restrict__ sn_b,
    const float* __restrict__ sg_w,  const float* __restrict__ sg_b,
    const float* __restrict__ ec_b,  const float* __restrict__ eg_w,
    float* __restrict__ ws, float* __restrict__ out){
  int blk = blockIdx.x, t = threadIdx.x;
  Scal* sc = (Scal*)(ws + OFF_SCAL);
  __shared__ float red[256];
  __shared__ float hbuf[256];
  __shared__ float sv[256*3];
  __shared__ int   si[256*3];

  if (blk == 64){
    // novelty outputs + sc->nov_mean (for decide logic later)
    const unsigned* gms = (const unsigned*)(ws + OFF_MAXSIM);
    float nv = 0.0f;
    if (t < 64){
      float msim = mono2f(gms[t]);
      nv = (1.0f - msim) * 0.5f;
      out[OUT_NOV + t] = nv;
    }
    red[t] = (t < 64) ? nv : 0.0f;
    __syncthreads();
    for (int o=128;o>0;o>>=1){ if (t<o) red[t]+=red[t+o]; __syncthreads(); }
    if (t == 0) sc->nov_mean = red[0] / 64.0f;
    return;
  }
  if (blk < 64){
    // ---- mlp1b: sum 8 h-partials, LN, split r-dot, nf from partials, store gate ----
    int b = blk;
    float h = sr_b1[t];
    #pragma unroll
    for (int s=0;s<8;s++) h += ws[OFF_HM + (s*64 + b)*256 + t];
    red[t] = h; __syncthreads();
    for (int o=128;o>0;o>>=1){ if (t<o) red[t]+=red[t+o]; __syncthreads(); }
    float mean = red[0] / 256.0f;
    __syncthreads();
    float dx = h - mean;
    red[t] = dx*dx; __syncthreads();
    for (int o=128;o>0;o>>=1){ if (t<o) red[t]+=red[t+o]; __syncthreads(); }
    float var = red[0] / 256.0f;
    __syncthreads();
    float hn = dx / sqrtf(var + 1e-5f) * sr_g[t] + sr_beta[t];
    hbuf[t] = fmaxf(hn, 0.0f);
    __syncthreads();
    // r partial: all 256 threads; output o = t&127, j-half jh = t>>7
    int oo = t & 127, jh = t >> 7;
    float rp = 0.f;
    const float* w2 = sr_w2 + (jh*128)*128 + oo;
    #pragma unroll 8
    for (int j=0;j<128;j++) rp = fmaf(hbuf[jh*128 + j], w2[j*128], rp);
    red[t] = rp;
    __syncthreads();
    float val = 0.0f;
    if (t < 128){
      float r = fmaxf(red[t] + red[t+128] + sr_b2[t], 0.0f);
      float nfl = sn_b[t];
      #pragma unroll
      for (int q=0;q<8;q++) nfl += ws[OFF_SNP + (((q>>1)*64 + b)*2 + (q&1))*128 + t];
      float nf = sigmoidf_(nfl);
      val = (r + nf) * sg_w[t];
    }
    __syncthreads();
    red[t] = val;                  // t>=128 contribute 0
    __syncthreads();
    for (int o=128;o>0;o>>=1){ if (t<o) red[t]+=red[t+o]; __syncthreads(); }
    if (t == 0){
      float ssc = sigmoidf_(red[0] + sg_b[0]);
      out[OUT_SS + b] = ssc;
      ws[OFF_STORES + b] = ssc;
    }
    return;
  }
  if (blk == 65){
    // ---- victimfix ----
    float capacity = (float)sc->cnt_active / 65536.0f;
    int de = (capacity > 0.85f) ? 1 : 0;
    int victim = (int)(0xFFFFFFFFu - (unsigned)(sc->victim_pack & 0xFFFFFFFFULL));
    if (t == 0){ sc->do_erase = de; sc->victim_idx = victim; }
    if (de){
      for (int d=t; d<512; d+=256) out[OUT_MEM + victim*512 + d] = 0.0f;
      if (t == 0){
        out[OUT_AT + victim] = -99999.0f;
        touch_row(victim, ws);
        float sum = 0.0f;
        for (int j=0;j<32;j++) sum += sigmoidf_(ec_b[j]) * eg_w[32 + j];
        ws[OFF_CONF + victim] = sum;
      }
    }
    return;
  }
  if (blk < 578){
    // ---- cond count; nov_mean re-reduced locally (removes dep on block 64) ----
    const unsigned* gms = (const unsigned*)(ws + OFF_MAXSIM);
    red[t] = (t < 64) ? (1.0f - mono2f(gms[t])) * 0.5f : 0.0f;
    __syncthreads();
    for (int o=128;o>0;o>>=1){ if (t<o) red[t]+=red[t+o]; __syncthreads(); }
    float thr = 1.0f - red[0] / 64.0f;
    const unsigned* simsu = (const unsigned*)(ws + OFF_SIMS);
    const float* norms = ws + OFF_NORMS;
    int gid = (blk - 66)*256 + t;
    int gstride = 512*256;
    int cnt = 0;
    for (int idx = gid; idx < B_N*S_N/2; idx += gstride){
      unsigned u = simsu[idx];
      int s = (idx*2) & (S_N-1);
      float v0 = __uint_as_float(u<<16);
      float v1 = __uint_as_float(u & 0xffff0000u);
      if (v0 > thr && norms[s]   > 0.5f) cnt++;
      if (v1 > thr && norms[s+1] > 0.5f) cnt++;
    }
    __syncthreads();
    int* redc = (int*)red;
    redc[t] = cnt;
    __syncthreads();
    for (int o=128;o>0;o>>=1){ if (t<o) redc[t]+=redc[t+o]; __syncthreads(); }
    if (t == 0) atomicAdd(&sc->cond_cnt, redc[0]);
    return;
  }
  // ---- top3: b = blk - 578; victim/do_erase decoded locally from phase1/k_victim results ----
  {
    int b = blk - 578;
    int victim = (int)(0xFFFFFFFFu - (unsigned)(sc->victim_pack & 0xFFFFFFFFULL));
    int de = (((float)sc->cnt_active / 65536.0f) > 0.85f) ? 1 : 0;
    const unsigned short* simrow = (const unsigned short*)(ws + OFF_SIMS) + (size_t)b*S_N;
    float v[3] = {-1e30f,-1e30f,-1e30f};
    int ix[3] = {INT_MAX, INT_MAX, INT_MAX};
    for (int s = t; s < S_N; s += 256){
      float val = bf2f(simrow[s]);
      if (de && s == victim) val = 0.0f;
      if (betterVI(val, s, v[2], ix[2])){
        if (betterVI(val, s, v[1], ix[1])){
          if (betterVI(val, s, v[0], ix[0])){
            v[2]=v[1]; ix[2]=ix[1]; v[1]=v[0]; ix[1]=ix[0]; v[0]=val; ix[0]=s;
          } else { v[2]=v[1]; ix[2]=ix[1]; v[1]=val; ix[1]=s; }
        } else { v[2]=val; ix[2]=s; }
      }
    }
    for (int r=0;r<3;r++){ sv[t*3+r]=v[r]; si[t*3+r]=ix[r]; }
    for (int off=128; off>0; off>>=1){
      __syncthreads();
      if (t < off){
        float av[3], bv[3], ov[3]; int ai[3], bi[3], oi[3];
        for (int r=0;r<3;r++){ av[r]=sv[t*3+r]; ai[r]=si[t*3+r]; bv[r]=sv[(t+off)*3+r]; bi[r]=si[(t+off)*3+r]; }
        int ap=0, bp=0;
        for (int r=0;r<3;r++){
          bool takeA = (bp>=3) || (ap<3 && betterVI(av[ap],ai[ap],bv[bp],bi[bp]));
          if (takeA){ ov[r]=av[ap]; oi[r]=ai[ap]; ap++; }
          else      { ov[r]=bv[bp]; oi[r]=bi[bp]; bp++; }
        }
        for (int r=0;r<3;r++){ sv[t*3+r]=ov[r]; si[t*3+r]=oi[r]; }
      }
    }
    __syncthreads();
    if (t == 0){
      for (int k=0;k<3;k++){
        ws[OFF_TV + b*3 + k] = sv[k];
        ((int*)(ws + OFF_TI))[b*3 + k] = si[k];
      }
    }
  }
}

// ================= k_mlp2: dedup MLP hidden partials, k-split x4 =================
__global__ __launch_bounds__(256) void k_mlp2(const float* __restrict__ nc,
    const float* __restrict__ dd_w1, const float* __restrict__ ds_w1,
    float* __restrict__ ws, float* __restrict__ out){
  int blk = blockIdx.x, t = threadIdx.x;
  int b = blk >> 2, ks = blk & 3;
  __shared__ float ch[3*256];
  if (ks < 2){
    ch[t] = nc[b*512 + ks*256 + t];
    __syncthreads();
    float hd = 0.f, hs = 0.f;
    const float* wd = dd_w1 + (ks*256)*256 + t;
    const float* wq = ds_w1 + (ks*256)*256 + t;
    #pragma unroll 4
    for (int i=0;i<256;i++){
      float c = ch[i];
      hd = fmaf(c, wd[i*256], hd);
      hs = fmaf(c, wq[i*256], hs);
    }
    float* H = ws + OFF_HNC + ((ks*64 + b)*2)*256;
    H[t] = hd; H[256 + t] = hs;
  } else {
    int ks2 = ks - 2;
    const int* tip = (const int*)(ws + OFF_TI);
    int r0 = tip[b*3], r1 = tip[b*3+1], r2 = tip[b*3+2];
    ch[t]       = out[OUT_MEM + (size_t)r0*512 + ks2*256 + t];
    ch[256 + t] = out[OUT_MEM + (size_t)r1*512 + ks2*256 + t];
    ch[512 + t] = out[OUT_MEM + (size_t)r2*512 + ks2*256 + t];
    __syncthreads();
    float hd0=0,hd1=0,hd2=0,hs0=0,hs1=0,hs2=0;
    const float* wd = dd_w1 + (512 + ks2*256)*256 + t;
    const float* wq = ds_w1 + (512 + ks2*256)*256 + t;
    #pragma unroll 4
    for (int i=0;i<256;i++){
      float w0 = wd[i*256], w1 = wq[i*256];
      float c0 = ch[i], c1 = ch[256+i], c2 = ch[512+i];
      hd0=fmaf(c0,w0,hd0); hd1=fmaf(c1,w0,hd1); hd2=fmaf(c2,w0,hd2);
      hs0=fmaf(c0,w1,hs0); hs1=fmaf(c1,w1,hs1); hs2=fmaf(c2,w1,hs2);
    }
    float* H = ws + OFF_HG;
    int p0 = b*3;
    H[((ks2*192 + p0+0)*2+0)*256 + t] = hd0;
    H[((ks2*192 + p0+1)*2+0)*256 + t] = hd1;
    H[((ks2*192 + p0+2)*2+0)*256 + t] = hd2;
    H[((ks2*192 + p0+0)*2+1)*256 + t] = hs0;
    H[((ks2*192 + p0+1)*2+1)*256 + t] = hs1;
    H[((ks2*192 + p0+2)*2+1)*256 + t] = hs2;
  }
}

// ================= k_pairfin: combine partials, decide apply, emit candidates =================
__global__ __launch_bounds__(256) void k_pairfin(const float* __restrict__ nc,
    const float* __restrict__ dd_b1, const float* __restrict__ dd_w2, const float* __restrict__ dd_b2,
    const float* __restrict__ ds_b1, const float* __restrict__ ds_w2, const float* __restrict__ ds_b2,
    float* __restrict__ ws, float* __restrict__ out){
  int p = blockIdx.x, t = threadIdx.x;
  int b = p / 3, k = p - 3*b;
  const int* tip = (const int*)(ws + OFF_TI);
  int row = tip[p];
  float hd = ws[OFF_HNC + ((0*64+b)*2+0)*256 + t] + ws[OFF_HNC + ((1*64+b)*2+0)*256 + t]
           + ws[OFF_HG + ((0*192+p)*2+0)*256 + t] + ws[OFF_HG + ((1*192+p)*2+0)*256 + t] + dd_b1[t];
  float hs = ws[OFF_HNC + ((0*64+b)*2+1)*256 + t] + ws[OFF_HNC + ((1*64+b)*2+1)*256 + t]
           + ws[OFF_HG + ((0*192+p)*2+1)*256 + t] + ws[OFF_HG + ((1*192+p)*2+1)*256 + t] + ds_b1[t];
  __shared__ float red[256];
  __shared__ float bc[2];
  red[t] = fmaxf(hd, 0.f) * dd_w2[t];
  __syncthreads();
  for (int o=128;o>0;o>>=1){ if (t<o) red[t]+=red[t+o]; __syncthreads(); }
  if (t == 0) bc[0] = red[0] + dd_b2[0];
  __syncthreads();
  red[t] = fmaxf(hs, 0.f) * ds_w2[t];
  __syncthreads();
  for (int o=128;o>0;o>>=1){ if (t<o) red[t]+=red[t+o]; __syncthreads(); }
  if (t == 0) bc[1] = red[0] + ds_b2[0];
  __syncthreads();
  float prob  = sigmoidf_(bc[0]);
  float stren = sigmoidf_(bc[1]);
  float tvv = ws[OFF_TV + p];
  int ap = (tvv > 0.7f && tvv < 0.99f && prob > 0.5f) ? 1 : 0;
  if (t == 0){
    ((int*)(ws + OFF_APPLY))[p] = ap;
    touch_row(row, ws);
  }
  for (int d=t; d<512; d+=256){
    float n = nc[b*512 + d];
    float g = out[OUT_MEM + (size_t)row*512 + d];
    float avg = 0.5f*(n + g);
    ws[OFF_DOCAND + p*512 + d] = (1.0f - stren)*g + stren*avg;
    if (b == 0) ws[OFF_DNC0 + k*512 + d] = (1.0f - stren)*n + stren*avg;
  }
}

// ================= k_scer: scatter (blk 0..1) + erase (blk 2..129) =================
__global__ __launch_bounds__(256) void k_scer(const int* __restrict__ step_p,
    const float* __restrict__ el_w, const float* __restrict__ el_b,
    const float* __restrict__ eg_w, const float* __restrict__ eg_b,
    float* __restrict__ ws, float* __restrict__ out){
  int blk = blockIdx.x, t = threadIdx.x;
  Scal* sc = (Scal*)(ws + OFF_SCAL);
  __shared__ unsigned long long rm[256], rs[256];
  if (blk < 2){
    // ---- scatter: columns independent; batch order serialized per column ----
    int d = blk*256 + t;   // 512 columns
    const int* tip = (const int*)(ws + OFF_TI);
    const int* ap  = (const int*)(ws + OFF_APPLY);
    for (int k=0;k<3;k++){
      float cur[64];
      #pragma unroll
      for (int b=0;b<64;b++) cur[b] = out[OUT_MEM + (size_t)tip[b*3 + k]*512 + d];
      #pragma unroll
      for (int b=0;b<64;b++){
        int p = b*3 + k;
        float v = ap[p] ? ws[OFF_DOCAND + p*512 + d] : cur[b];
        out[OUT_MEM + (size_t)tip[p]*512 + d] = v;
      }
    }
    return;
  }
  // ---- erase (128 blocks) ----
  float stepf = (float)step_p[0];
  float egb = eg_b[0];
  int gid = (blk-2)*256 + t;
  int gstride = 128*256;
  unsigned long long bm = 0ULL, bs = 0ULL;
  for (int s = gid; s < S_N; s += gstride){
    float a = out[OUT_AT + s];
    float x = (stepf - a) / 1000.0f;
    float lp = 0.0f;
    #pragma unroll
    for (int j=0;j<32;j++) lp += fmaxf(x*el_w[j] + el_b[j], 0.0f) * eg_w[j];
    float er = sigmoidf_(lp + ws[OFF_CONF + s] + egb);
    float sa = stepf - a;
    bool recent = (a >= 0.0f) && (sa < 3.0f);
    float msk = recent ? 0.0f : er;
    ws[OFF_ERSC + s] = er;
    ws[OFF_MASKED + s] = msk;
    ws[OFF_SLOTAGE + s] = sa;
    unsigned long long pm = packvi(msk, s); if (pm > bm) bm = pm;
    unsigned long long ps = packvi(sa,  s); if (ps > bs) bs = ps;
  }
  rm[t]=bm; rs[t]=bs; __syncthreads();
  for (int o=128;o>0;o>>=1){
    if (t<o){ if (rm[t+o]>rm[t]) rm[t]=rm[t+o]; if (rs[t+o]>rs[t]) rs[t]=rs[t+o]; }
    __syncthreads();
  }
  if (t == 0){
    atomicMax(&sc->masked_pack, rm[0]);
    atomicMax(&sc->slotage_pack, rs[0]);
  }
}

// ================= k_finalout: decide-logic recomputed per block =================
__global__ __launch_bounds__(256) void k_finalout(const float* __restrict__ nc,
                                                  const int* __restrict__ step_p,
                                                  float* __restrict__ ws, float* __restrict__ out){
  int blk = blockIdx.x, t = threadIdx.x;
  Scal* sc = (Scal*)(ws + OFF_SCAL);
  __shared__ float red[64];
  __shared__ int sh_ss, sh_wi;
  if (t < 64) red[t] = ws[OFF_STORES + t];
  __syncthreads();
  for (int o=32;o>0;o>>=1){ if (t<o) red[t]+=red[t+o]; __syncthreads(); }
  if (t == 0){
    float store_mean = red[0] / 64.0f;
    int cnt = sc->cnt_active;
    float capacity = (float)cnt / 65536.0f;
    float dyn_thr;
    if (capacity < 0.3f) dyn_thr = 0.08f;
    else if (capacity < 0.6f) dyn_thr = 0.08f + (capacity - 0.3f)*0.733f;
    else dyn_thr = 0.3f + (capacity - 0.6f);
    dyn_thr = fminf(fmaxf(dyn_thr, 0.0f), 0.7f);
    float topk_thr = (capacity < 0.3f) ? 0.1f : ((capacity < 0.6f) ? 0.2f : 0.4f);
    float raw_thr  = (capacity < 0.3f) ? 0.3f : 0.5f;
    int base_store = store_mean > raw_thr;
    int novelty_ok = sc->nov_mean > dyn_thr;
    int cmax = cnt > 1 ? cnt : 1;
    float denom = (float)(64 * cmax);
    float perc = (cnt > 0) ? ((float)sc->cond_cnt) / denom : 1.0f;
    int topk_ok = perc > topk_thr;
    int de = sc->do_erase;
    int ss = base_store && novelty_ok && topk_ok;
    if (de && !novelty_ok) ss = 0;
    float mmax = mono2f((unsigned)(sc->masked_pack >> 32));
    int marg = (int)(0xFFFFFFFFu - (unsigned)(sc->masked_pack  & 0xFFFFFFFFULL));
    int sarg = (int)(0xFFFFFFFFu - (unsigned)(sc->slotage_pack & 0xFFFFFFFFULL));
    sh_ss = ss;
    sh_wi = de ? sc->victim_idx : ((mmax > 0.0f) ? marg : sarg);
  }
  __syncthreads();
  int ss = sh_ss, de = sc->do_erase;
  if (blk == 64){
    if (ss){
      int wi = sh_wi;
      const int* ap = (const int*)(ws + OFF_APPLY);
      for (int d=t; d<512; d+=256){
        float v = nc[d];               // b = 0 row
        if (ap[0]) v = ws[OFF_DNC0 + 0*512 + d];
        if (ap[1]) v = ws[OFF_DNC0 + 1*512 + d];
        if (ap[2]) v = ws[OFF_DNC0 + 2*512 + d];
        out[OUT_MEM + (size_t)wi*512 + d] = v;
      }
      if (t == 0){
        out[OUT_AT + wi] = (float)step_p[0];
        touch_row(wi, ws);
      }
    }
    return;
  }
  float mmax = mono2f((unsigned)(sc->masked_pack >> 32));
  bool usemask = ss && !de;
  for (int s = blk*256 + t; s < S_N; s += 64*256){
    float v;
    if (usemask) v = (mmax <= 0.0f) ? ws[OFF_SLOTAGE + s] : ws[OFF_MASKED + s];
    else v = ws[OFF_ERSC + s];
    out[OUT_ER + s] = v;
  }
}

// ================= k_diff: |out_mem - mem| over touched rows; rc folded in =================
__global__ __launch_bounds__(256) void k_diff(const float* __restrict__ mem,
                                              float* __restrict__ ws, float* __restrict__ out){
  int t = threadIdx.x;
  Scal* sc = (Scal*)(ws + OFF_SCAL);
  int cnt = sc->list_cnt;
  const int* list = (const int*)(ws + OFF_LIST);
  float lsum = 0.0f;
  for (int i = blockIdx.x; i < cnt; i += gridDim.x){
    int row = list[i];
    float part = 0.0f;
    for (int d=t; d<512; d+=256)
      part += fabsf(out[OUT_MEM + (size_t)row*512 + d] - mem[(size_t)row*512 + d]);
    lsum += part;
  }
  __shared__ float red[256];
  red[t] = lsum; __syncthreads();
  for (int o=128;o>0;o>>=1){ if (t<o) red[t]+=red[t+o]; __syncthreads(); }
  if (t == 0 && red[0] != 0.0f) atomicAdd(out + OUT_RC, red[0] * (1.0f/33554432.0f));
}

// ================= host =================
extern "C" void kernel_launch(void* const* d_in, const int* in_sizes, int n_in,
                              void* d_out, int out_size, void* d_ws, size_t ws_size,
                              hipStream_t stream) {
  const float* nc    = (const float*)d_in[0];
  const float* qr    = (const float*)d_in[1];
  const float* mem   = (const float*)d_in[2];
  const float* at    = (const float*)d_in[3];
  const int*   step  = (const int*)  d_in[4];
  const float* sr_w1 = (const float*)d_in[5];
  const float* sr_b1 = (const float*)d_in[6];
  const float* sr_g  = (const float*)d_in[7];
  const float* sr_be = (const float*)d_in[8];
  const float* sr_w2 = (const float*)d_in[9];
  const float* sr_b2 = (const float*)d_in[10];
  const float* sn_w  = (const float*)d_in[11];
  const float* sn_b  = (const float*)d_in[12];
  const float* sg_w  = (const float*)d_in[13];
  const float* sg_b  = (const float*)d_in[14];
  const float* el_w  = (const float*)d_in[15];
  const float* el_b  = (const float*)d_in[16];
  const float* ec_w  = (const float*)d_in[17];
  const float* ec_b  = (const float*)d_in[18];
  const float* eg_w  = (const float*)d_in[19];
  const float* eg_b  = (const float*)d_in[20];
  const float* dd_w1 = (const float*)d_in[21];
  const float* dd_b1 = (const float*)d_in[22];
  const float* dd_w2 = (const float*)d_in[23];
  const float* dd_b2 = (const float*)d_in[24];
  const float* ds_w1 = (const float*)d_in[25];
  const float* ds_b1 = (const float*)d_in[26];
  const float* ds_w2 = (const float*)d_in[27];
  const float* ds_b2 = (const float*)d_in[28];
  float* out = (float*)d_out;
  float* ws  = (float*)d_ws;

  k_initm    <<<dim3(1057), dim3(256), 0, stream>>>(nc, qr, at, ec_w, step, sr_w1, sn_w, ws, out);
  k_phase1   <<<dim3(1024), dim3(256), 0, stream>>>(mem, ec_b, eg_w, ws, out);
  k_victim   <<<dim3(64), dim3(256), 0, stream>>>(at, step, ws);
  k_mid      <<<dim3(642), dim3(256), 0, stream>>>(nc, qr, sr_b1, sr_g, sr_be,
                                                   sr_w2, sr_b2, sn_b, sg_w, sg_b,
                                                   ec_b, eg_w, ws, out);
  k_mlp2     <<<dim3(256), dim3(256), 0, stream>>>(nc, dd_w1, ds_w1, ws, out);
  k_pairfin  <<<dim3(192), dim3(256), 0, stream>>>(nc, dd_b1, dd_w2, dd_b2,
                                                   ds_b1, ds_w2, ds_b2, ws, out);
  k_scer     <<<dim3(130), dim3(256), 0, stream>>>(step, el_w, el_b, eg_w, eg_b, ws, out);
  k_finalout <<<dim3(65), dim3(256), 0, stream>>>(nc, step, ws, out);
  k_diff     <<<dim3(64), dim3(256), 0, stream>>>(mem, ws, out);
}

// Round 7
// 474.516 us; speedup vs baseline: 1.0639x; 1.0639x over previous
//
#include <hip/hip_runtime.h>
#include <math.h>
#include <limits.h>

#define S_N 65536
#define D_N 512
#define B_N 64

typedef __attribute__((ext_vector_type(8))) short short8;
typedef __attribute__((ext_vector_type(4))) float f32x4;

// ---------------- workspace layout (float indices) ----------------
#define SIMS_F      (B_N*S_N/2)                 // bf16 sims stored as ushort
#define OFF_SIMS    0
#define OFF_AEXT    (OFF_SIMS + SIMS_F)         // ushort[96*512]: rows 0..63 norm(nc), 64..95 ec_w^T (bf16)
#define AEXT_F      (96*512/2)
#define OFF_NORMS   (OFF_AEXT + AEXT_F)
#define OFF_CONF    (OFF_NORMS + S_N)
#define OFF_FLAGS   (OFF_CONF + S_N)            // int
#define OFF_LIST    (OFF_FLAGS + S_N)           // int[256] touched rows
#define OFF_MASKED  (OFF_LIST + 256)
#define OFF_ERSC    (OFF_MASKED + S_N)
#define OFF_SLOTAGE (OFF_ERSC + S_N)
#define OFF_STORES  (OFF_SLOTAGE + S_N)         // 64
#define OFF_MAXSIM  (OFF_STORES + 64)           // 64 u32 mono
#define OFF_TI      (OFF_MAXSIM + 64)           // 192 int
#define OFF_TV      (OFF_TI + 192)              // 192
#define OFF_APPLY   (OFF_TV + 192)              // 192 int
#define OFF_HM      (OFF_APPLY + 192)           // mlp1 partials [8][64][256] (spills into HNC/HG space;
                                                //   safe: initm writes, k_mid reads, then k_mlp2 overwrites)
#define OFF_HNC     (OFF_HM + 32768)            // 2*64*2*256 mlp2 nc-half partials
#define OFF_HG      (OFF_HNC + 65536)           // 2*192*2*256 mlp2 gathered-half partials
#define OFF_DNC0    (OFF_HG + 196608)           // 3*512
#define OFF_DRIFT0  (OFF_DNC0 + 1536)           // 512
#define OFF_DOCAND  (OFF_DRIFT0 + 512)          // 192*512
#define OFF_SNP     OFF_DOCAND                  // [4][64][2][128] nf partials (initm writes, mlp1b reads,
                                                //   only then pairfin overwrites DOCAND)
#define OFF_SCAL    (OFF_DOCAND + 98304)

// ---------------- output layout (floats) ----------------
#define OUT_MEM 0
#define OUT_AT  (S_N*D_N)
#define OUT_ER  (OUT_AT + S_N)
#define OUT_SS  (OUT_ER + S_N)
#define OUT_NOV (OUT_SS + 64)
#define OUT_RC  (OUT_NOV + 64)

struct __align__(8) Scal {
  unsigned long long victim_pack;
  unsigned long long masked_pack;
  unsigned long long slotage_pack;
  int cnt_active;
  int cond_cnt;
  unsigned age_max_t;
  float nov_mean;
  float changed_sum;
  int do_erase;
  int should_store;
  int write_idx;
  int victim_idx;
  int list_cnt;
};

__device__ __forceinline__ float sigmoidf_(float x){ return 1.0f/(1.0f+expf(-x)); }
__device__ __forceinline__ unsigned f2mono(float f){
  unsigned u = __float_as_uint(f);
  return (u & 0x80000000u) ? ~u : (u | 0x80000000u);
}
__device__ __forceinline__ float mono2f(unsigned m){
  unsigned u = (m & 0x80000000u) ? (m & 0x7FFFFFFFu) : ~m;
  return __uint_as_float(u);
}
__device__ __forceinline__ unsigned long long packvi(float v, int i){
  return (((unsigned long long)f2mono(v)) << 32) | (unsigned long long)(0xFFFFFFFFu - (unsigned)i);
}
__device__ __forceinline__ bool betterVI(float v, int i, float v2, int i2){
  return (v > v2) || (v == v2 && i < i2);
}
__device__ __forceinline__ unsigned short bf16r(float f){   // RNE f32->bf16
  unsigned u = __float_as_uint(f);
  return (unsigned short)((u + 0x7fffu + ((u>>16)&1u)) >> 16);
}
__device__ __forceinline__ float bf2f(unsigned short h){
  return __uint_as_float(((unsigned)h)<<16);
}
__device__ __forceinline__ void touch_row(int row, float* ws){
  int* flags = (int*)(ws + OFF_FLAGS);
  if (atomicExch(&flags[row], 1) == 0){
    Scal* sc = (Scal*)(ws + OFF_SCAL);
    int i = atomicAdd(&sc->list_cnt, 1);
    ((int*)(ws + OFF_LIST))[i] = row;
  }
}

// async global->LDS, 16B per lane. dest = wave-uniform base + lane*16; src per-lane.
__device__ __forceinline__ void gld16(const float* g, void* l){
  __builtin_amdgcn_global_load_lds((const __attribute__((address_space(1))) void*)g,
                                   (__attribute__((address_space(3))) void*)l, 16, 0, 0);
}
#define WAITV(N) asm volatile("s_waitcnt vmcnt(" #N ")" ::: "memory")

// ================= k_initm: init (289) + mlp1a ksplit8 (512) + nf partials (256) =================
__global__ __launch_bounds__(256) void k_initm(const float* __restrict__ nc,
                                               const float* __restrict__ qr,
                                               const float* __restrict__ at_in,
                                               const float* __restrict__ ec_w,
                                               const int* __restrict__ step_p,
                                               const float* __restrict__ sr_w1,
                                               const float* __restrict__ sn_w,
                                               float* __restrict__ ws, float* __restrict__ out){
  int blk = blockIdx.x, t = threadIdx.x;
  Scal* sc = (Scal*)(ws + OFF_SCAL);
  unsigned short* aB = (unsigned short*)(ws + OFF_AEXT);
  __shared__ float red[256];
  __shared__ float ch[256];
  if (blk == 0){
    if (t == 0){
      sc->victim_pack = 0ULL; sc->masked_pack = 0ULL; sc->slotage_pack = 0ULL;
      sc->cnt_active = 0; sc->cond_cnt = 0; sc->age_max_t = 0u;
      sc->nov_mean = 0.0f; sc->changed_sum = 0.0f;
      sc->do_erase = 0; sc->should_store = 0; sc->write_idx = 0; sc->victim_idx = 0;
      sc->list_cnt = 0;
      out[OUT_RC] = 0.0f;           // k_diff atomicAdds into this
    }
    if (t < 64) ((unsigned*)(ws + OFF_MAXSIM))[t] = 0u;
  } else if (blk <= 64){
    int b = blk - 1;
    float x0 = nc[b*512 + t], x1 = nc[b*512 + 256 + t];
    red[t] = x0*x0 + x1*x1;
    __syncthreads();
    for (int o=128;o>0;o>>=1){ if (t<o) red[t]+=red[t+o]; __syncthreads(); }
    float inv = 1.0f / fmaxf(sqrtf(red[0]), 1e-12f);
    aB[b*512 + t]       = bf16r(x0*inv);
    aB[b*512 + 256 + t] = bf16r(x1*inv);
  } else if (blk <= 96){
    int j = blk - 65;
    for (int d=t; d<512; d+=256) aB[(64+j)*512 + d] = bf16r(ec_w[d*32 + j]);
  } else if (blk <= 160){
    int part = blk - 97;
    float stepf = (float)step_p[0];
    float lmaxv = -1e30f;
    for (int s = part*1024 + t; s < (part+1)*1024; s += 256)
      lmaxv = fmaxf(lmaxv, fmaxf(stepf - at_in[s], 0.0f));
    red[t]=lmaxv; __syncthreads();
    for (int o=128;o>0;o>>=1){ if (t<o) red[t]=fmaxf(red[t],red[t+o]); __syncthreads(); }
    if (t==0) atomicMax(&sc->age_max_t, f2mono(red[0]));
  } else if (blk <= 224){
    int part = blk - 161;
    for (int s = part*1024 + t; s < (part+1)*1024; s += 256)
      out[OUT_AT + s] = at_in[s];
  } else if (blk <= 288){
    int part = blk - 225;   // 64 parts
    int* flags = (int*)(ws + OFF_FLAGS);
    for (int s = part*1024 + t; s < (part+1)*1024; s += 256) flags[s] = 0;
  } else if (blk <= 800){
    // ---- mlp1a: h partials, k-split 8 (512 blocks, 128-iter loops) ----
    int blk2 = blk - 289;             // 0..511
    int b = blk2 >> 3, s = blk2 & 7;
    const float* src = (s < 4) ? nc : qr;
    if (t < 128) ch[t] = src[b*512 + (s & 3)*128 + t];
    __syncthreads();
    float h = 0.f;
    const float* w = sr_w1 + (s*128)*256 + t;
    #pragma unroll 8
    for (int i=0;i<128;i++) h = fmaf(ch[i], w[i*256], h);
    ws[OFF_HM + (s*64 + b)*256 + t] = h;
  } else {
    // ---- nf (sn_w) partials: [ks 0..3][b][kh 0..1][128], 64-iter loops, all 256 threads ----
    int blk2 = blk - 801;             // 0..255
    int b = blk2 >> 2, ks = blk2 & 3;
    int o = t & 127, kh = t >> 7;
    if (t < 128) ch[t] = nc[b*512 + ks*128 + t];
    __syncthreads();
    float p = 0.f;
    const float* w = sn_w + (ks*128 + kh*64)*128 + o;
    #pragma unroll 8
    for (int i=0;i<64;i++) p = fmaf(ch[kh*64 + i], w[i*128], p);
    ws[OFF_SNP + ((ks*64 + b)*2 + kh)*128 + o] = p;
  }
}

// ================= k_phase1: FROZEN internals (R2/R5 99-103 us version). Only change:
// half-grid dispatch via s_base (SGPR int, no memory ops) so top-5 profiling exposes
// the tail kernels. s0 = (blockIdx.x + s_base)*64.
__global__ __launch_bounds__(256) void k_phase1(const float* __restrict__ mem,
                                                const float* __restrict__ ec_b,
                                                const float* __restrict__ eg_w,
                                                float* __restrict__ ws, float* __restrict__ out,
                                                int s_base){
  __shared__ __align__(16) unsigned short aT[96*520];   // 99840 B, padded rows
  __shared__ __align__(16) char chunks[4*4*2048];       // 4 waves x 4 bufs x 2KB
  __shared__ unsigned lmax[64];
  int t = threadIdx.x;
  int s0 = (blockIdx.x + s_base) * 64;
  Scal* sc = (Scal*)(ws + OFF_SCAL);
  int lane = t & 63, wv = t >> 6;
  int quad = lane >> 4, l15 = lane & 15;
  int row = wv*16 + l15;                 // mem row this lane consumes == its sims column

  // ---- stage Aext (bf16) global ws -> padded LDS; 6144 uint4 total ----
  {
    const uint4* src = (const uint4*)(ws + OFF_AEXT);
    #pragma unroll
    for (int i=0;i<24;i++){
      int idx = i*256 + t;
      int arow = idx >> 6, c16 = idx & 63;
      uint4 v = src[idx];
      *(uint4*)((char*)aT + arow*1040 + c16*16) = v;
    }
    if (t < 64) lmax[t] = 0u;
  }
  __syncthreads();   // drains vmcnt/lgkmcnt -> clean FIFO for counted waits below

  const float* gsrc = mem + ((size_t)(s0 + row))*512 + quad*8;
  float* od = out + OUT_MEM + ((size_t)(s0 + row))*512 + quad*8;
  char* mybuf = chunks + wv*8192;
  #define STAGE(c) do{ \
    gld16(gsrc + (c)*32,     mybuf + ((c)&3)*2048); \
    gld16(gsrc + (c)*32 + 4, mybuf + ((c)&3)*2048 + 1024); \
  }while(0)

  STAGE(0); asm volatile("" ::: "memory");
  STAGE(1); asm volatile("" ::: "memory");
  STAGE(2); asm volatile("" ::: "memory");

  f32x4 acc[6];
  #pragma unroll
  for (int r=0;r<6;r++) acc[r] = (f32x4){0.f,0.f,0.f,0.f};
  float ssq = 0.f;

  #pragma unroll
  for (int c=0;c<16;c++){
    if (c < 13) STAGE(c+3);
    if      (c == 0)  WAITV(6);
    else if (c == 1)  WAITV(8);
    else if (c == 2)  WAITV(10);
    else if (c <= 12) WAITV(12);
    else if (c == 13) WAITV(10);
    else if (c == 14) WAITV(8);
    else              WAITV(6);
    __builtin_amdgcn_sched_barrier(0);
    const char* bp = mybuf + (c&3)*2048;
    float4 v0 = *(const float4*)(bp + lane*16);
    float4 v1 = *(const float4*)(bp + 1024 + lane*16);
    *(float4*)(od + c*32)     = v0;     // copy-out fused (2 stores/iter, counted above)
    *(float4*)(od + c*32 + 4) = v1;
    ssq = fmaf(v0.x,v0.x,ssq); ssq = fmaf(v0.y,v0.y,ssq);
    ssq = fmaf(v0.z,v0.z,ssq); ssq = fmaf(v0.w,v0.w,ssq);
    ssq = fmaf(v1.x,v1.x,ssq); ssq = fmaf(v1.y,v1.y,ssq);
    ssq = fmaf(v1.z,v1.z,ssq); ssq = fmaf(v1.w,v1.w,ssq);
    short8 bfrag;
    bfrag[0]=(short)bf16r(v0.x); bfrag[1]=(short)bf16r(v0.y);
    bfrag[2]=(short)bf16r(v0.z); bfrag[3]=(short)bf16r(v0.w);
    bfrag[4]=(short)bf16r(v1.x); bfrag[5]=(short)bf16r(v1.y);
    bfrag[6]=(short)bf16r(v1.z); bfrag[7]=(short)bf16r(v1.w);
    #pragma unroll
    for (int rt=0;rt<6;rt++){
      short8 afrag = *(const short8*)&aT[(rt*16 + l15)*520 + c*32 + quad*8];
      acc[rt] = __builtin_amdgcn_mfma_f32_16x16x32_bf16(afrag, bfrag, acc[rt], 0,0,0);
    }
  }
  #undef STAGE

  // ---- row norm: quads hold disjoint col-chunks of the same row ----
  ssq += __shfl_xor(ssq, 16);
  ssq += __shfl_xor(ssq, 32);
  float nrm = sqrtf(ssq);
  float lv = 1.0f / fmaxf(nrm, 1e-12f);
  if (quad == 0) ws[OFF_NORMS + s0 + row] = nrm;
  unsigned long long m = __ballot(quad==0 && nrm > 0.5f);
  if (lane == 0) atomicAdd(&sc->cnt_active, (int)__popcll(m));

  // ---- epilogue: D[a][s] col=l15(+wv*16+s0), row=quad*4+reg ----
  unsigned short* simsb = (unsigned short*)(ws + OFF_SIMS);
  #pragma unroll
  for (int rt=0;rt<4;rt++){
    #pragma unroll
    for (int r=0;r<4;r++){
      int a = rt*16 + quad*4 + r;
      float sim = acc[rt][r] * lv;
      simsb[(size_t)a*S_N + s0 + row] = bf16r(sim);
      atomicMax(&lmax[a], f2mono(sim));
    }
  }
  float cpart = 0.f;
  #pragma unroll
  for (int rt=4;rt<6;rt++){
    #pragma unroll
    for (int r=0;r<4;r++){
      int j = (rt-4)*16 + quad*4 + r;
      cpart += sigmoidf_(acc[rt][r] + ec_b[j]) * eg_w[32+j];
    }
  }
  cpart += __shfl_down(cpart, 32);
  cpart += __shfl_down(cpart, 16);
  if (lane < 16) ws[OFF_CONF + s0 + row] = cpart;
  __syncthreads();
  if (t < 64) atomicMax(((unsigned*)(ws + OFF_MAXSIM)) + t, lmax[t]);
}

// ================= k_victim: es argmax (separate kernel so phase1 codegen stays clean) =================
__global__ __launch_bounds__(256) void k_victim(const float* __restrict__ at_in,
                                                const int* __restrict__ step_p,
                                                float* __restrict__ ws){
  int t = threadIdx.x;
  Scal* sc = (Scal*)(ws + OFF_SCAL);
  float stepf = (float)step_p[0];
  float agemax = mono2f(sc->age_max_t);
  const float* norms = ws + OFF_NORMS;
  int gid = blockIdx.x*256 + t;
  int gstride = gridDim.x*256;
  unsigned long long best = 0ULL;
  for (int s = gid; s < S_N; s += gstride){
    float age = fmaxf(stepf - at_in[s], 0.0f);
    float es = age/(agemax + 1e-6f) + (1.0f - sigmoidf_(norms[s]));
    unsigned long long pk = packvi(es, s);
    if (pk > best) best = pk;
  }
  __shared__ unsigned long long redp[256];
  redp[t] = best; __syncthreads();
  for (int o=128;o>0;o>>=1){
    if (t<o && redp[t+o] > redp[t]) redp[t] = redp[t+o];
    __syncthreads();
  }
  if (t == 0) atomicMax(&sc->victim_pack, redp[0]);
}

// ================= k_mid: mlp1b(0..64) + victimfix(65) + cond-scan(66..577) + top3(578..641) =================
__global__ __launch_bounds__(256) void k_mid(const float* __restrict__ nc, const float* __restrict__ qr,
    const float* __restrict__ sr_b1, const float* __restrict__ sr_g, const float* __restrict__ sr_beta,
    const float* __restrict__ sr_w2, const float* __restrict__ sr_b2,
    const float* __restrict__ sn_b,
    const float* __restrict__ sg_w,  const float* __restrict__ sg_b,
    const float* __restrict__ ec_b,  const float* __restrict__ eg_w,
    float* __restrict__ ws, float* __restrict__ out){
  int blk = blockIdx.x, t = threadIdx.x;
  Scal* sc = (Scal*)(ws + OFF_SCAL);
  __shared__ float red[256];
  __shared__ float hbuf[256];
  __shared__ float sv[256*3];
  __shared__ int   si[256*3];

  if (blk == 64){
    // novelty outputs + sc->nov_mean (for decide logic later)
    const unsigned* gms = (const unsigned*)(ws + OFF_MAXSIM);
    float nv = 0.0f;
    if (t < 64){
      float msim = mono2f(gms[t]);
      nv = (1.0f - msim) * 0.5f;
      out[OUT_NOV + t] = nv;
    }
    red[t] = (t < 64) ? nv : 0.0f;
    __syncthreads();
    for (int o=128;o>0;o>>=1){ if (t<o) red[t]+=red[t+o]; __syncthreads(); }
    if (t == 0) sc->nov_mean = red[0] / 64.0f;
    return;
  }
  if (blk < 64){
    // ---- mlp1b: sum 8 h-partials, LN, split r-dot, nf from partials, store gate ----
    int b = blk;
    float h = sr_b1[t];
    #pragma unroll
    for (int s=0;s<8;s++) h += ws[OFF_HM + (s*64 + b)*256 + t];
    red[t] = h; __syncthreads();
    for (int o=128;o>0;o>>=1){ if (t<o) red[t]+=red[t+o]; __syncthreads(); }
    float mean = red[0] / 256.0f;
    __syncthreads();
    float dx = h - mean;
    red[t] = dx*dx; __syncthreads();
    for (int o=128;o>0;o>>=1){ if (t<o) red[t]+=red[t+o]; __syncthreads(); }
    float var = red[0] / 256.0f;
    __syncthreads();
    float hn = dx / sqrtf(var + 1e-5f) * sr_g[t] + sr_beta[t];
    hbuf[t] = fmaxf(hn, 0.0f);
    __syncthreads();
    // r partial: all 256 threads; output o = t&127, j-half jh = t>>7
    int oo = t & 127, jh = t >> 7;
    float rp = 0.f;
    const float* w2 = sr_w2 + (jh*128)*128 + oo;
    #pragma unroll 8
    for (int j=0;j<128;j++) rp = fmaf(hbuf[jh*128 + j], w2[j*128], rp);
    red[t] = rp;
    __syncthreads();
    float val = 0.0f;
    if (t < 128){
      float r = fmaxf(red[t] + red[t+128] + sr_b2[t], 0.0f);
      float nfl = sn_b[t];
      #pragma unroll
      for (int q=0;q<8;q++) nfl += ws[OFF_SNP + (((q>>1)*64 + b)*2 + (q&1))*128 + t];
      float nf = sigmoidf_(nfl);
      val = (r + nf) * sg_w[t];
    }
    __syncthreads();
    red[t] = val;                  // t>=128 contribute 0
    __syncthreads();
    for (int o=128;o>0;o>>=1){ if (t<o) red[t]+=red[t+o]; __syncthreads(); }
    if (t == 0){
      float ssc = sigmoidf_(red[0] + sg_b[0]);
      out[OUT_SS + b] = ssc;
      ws[OFF_STORES + b] = ssc;
    }
    return;
  }
  if (blk == 65){
    // ---- victimfix ----
    float capacity = (float)sc->cnt_active / 65536.0f;
    int de = (capacity > 0.85f) ? 1 : 0;
    int victim = (int)(0xFFFFFFFFu - (unsigned)(sc->victim_pack & 0xFFFFFFFFULL));
    if (t == 0){ sc->do_erase = de; sc->victim_idx = victim; }
    if (de){
      for (int d=t; d<512; d+=256) out[OUT_MEM + victim*512 + d] = 0.0f;
      if (t == 0){
        out[OUT_AT + victim] = -99999.0f;
        touch_row(victim, ws);
        float sum = 0.0f;
        for (int j=0;j<32;j++) sum += sigmoidf_(ec_b[j]) * eg_w[32 + j];
        ws[OFF_CONF + victim] = sum;
      }
    }
    return;
  }
  if (blk < 578){
    // ---- cond count (uint4 = 8 sims/iter); nov_mean re-reduced locally ----
    const unsigned* gms = (const unsigned*)(ws + OFF_MAXSIM);
    red[t] = (t < 64) ? (1.0f - mono2f(gms[t])) * 0.5f : 0.0f;
    __syncthreads();
    for (int o=128;o>0;o>>=1){ if (t<o) red[t]+=red[t+o]; __syncthreads(); }
    float thr = 1.0f - red[0] / 64.0f;
    const uint4* sims4 = (const uint4*)(ws + OFF_SIMS);
    const float* norms = ws + OFF_NORMS;
    int gid = (blk - 66)*256 + t;
    int gstride = 512*256;
    int cnt = 0;
    for (int idx = gid; idx < B_N*S_N/8; idx += gstride){
      uint4 u = sims4[idx];
      int s = (idx*8) & (S_N-1);
      const float4* n4 = (const float4*)(norms + s);
      float4 na = n4[0], nb = n4[1];
      if (__uint_as_float(u.x<<16)          > thr && na.x > 0.5f) cnt++;
      if (__uint_as_float(u.x & 0xffff0000u) > thr && na.y > 0.5f) cnt++;
      if (__uint_as_float(u.y<<16)          > thr && na.z > 0.5f) cnt++;
      if (__uint_as_float(u.y & 0xffff0000u) > thr && na.w > 0.5f) cnt++;
      if (__uint_as_float(u.z<<16)          > thr && nb.x > 0.5f) cnt++;
      if (__uint_as_float(u.z & 0xffff0000u) > thr && nb.y > 0.5f) cnt++;
      if (__uint_as_float(u.w<<16)          > thr && nb.z > 0.5f) cnt++;
      if (__uint_as_float(u.w & 0xffff0000u) > thr && nb.w > 0.5f) cnt++;
    }
    __syncthreads();
    int* redc = (int*)red;
    redc[t] = cnt;
    __syncthreads();
    for (int o=128;o>0;o>>=1){ if (t<o) redc[t]+=redc[t+o]; __syncthreads(); }
    if (t == 0) atomicAdd(&sc->cond_cnt, redc[0]);
    return;
  }
  // ---- top3 (uint2 = 4 sims/iter): b = blk - 578 ----
  {
    int b = blk - 578;
    int victim = (int)(0xFFFFFFFFu - (unsigned)(sc->victim_pack & 0xFFFFFFFFULL));
    int de = (((float)sc->cnt_active / 65536.0f) > 0.85f) ? 1 : 0;
    const uint2* simrow2 = (const uint2*)((const unsigned short*)(ws + OFF_SIMS) + (size_t)b*S_N);
    float v[3] = {-1e30f,-1e30f,-1e30f};
    int ix[3] = {INT_MAX, INT_MAX, INT_MAX};
    for (int q = t; q < S_N/4; q += 256){
      uint2 u = simrow2[q];
      int s = q*4;
      float vals[4];
      vals[0] = __uint_as_float(u.x<<16);
      vals[1] = __uint_as_float(u.x & 0xffff0000u);
      vals[2] = __uint_as_float(u.y<<16);
      vals[3] = __uint_as_float(u.y & 0xffff0000u);
      #pragma unroll
      for (int r4=0;r4<4;r4++){
        float val = vals[r4];
        int ss = s + r4;
        if (de && ss == victim) val = 0.0f;
        if (betterVI(val, ss, v[2], ix[2])){
          if (betterVI(val, ss, v[1], ix[1])){
            if (betterVI(val, ss, v[0], ix[0])){
              v[2]=v[1]; ix[2]=ix[1]; v[1]=v[0]; ix[1]=ix[0]; v[0]=val; ix[0]=ss;
            } else { v[2]=v[1]; ix[2]=ix[1]; v[1]=val; ix[1]=ss; }
          } else { v[2]=val; ix[2]=ss; }
        }
      }
    }
    for (int r=0;r<3;r++){ sv[t*3+r]=v[r]; si[t*3+r]=ix[r]; }
    for (int off=128; off>0; off>>=1){
      __syncthreads();
      if (t < off){
        float av[3], bv[3], ov[3]; int ai[3], bi[3], oi[3];
        for (int r=0;r<3;r++){ av[r]=sv[t*3+r]; ai[r]=si[t*3+r]; bv[r]=sv[(t+off)*3+r]; bi[r]=si[(t+off)*3+r]; }
        int ap=0, bp=0;
        for (int r=0;r<3;r++){
          bool takeA = (bp>=3) || (ap<3 && betterVI(av[ap],ai[ap],bv[bp],bi[bp]));
          if (takeA){ ov[r]=av[ap]; oi[r]=ai[ap]; ap++; }
          else      { ov[r]=bv[bp]; oi[r]=bi[bp]; bp++; }
        }
        for (int r=0;r<3;r++){ sv[t*3+r]=ov[r]; si[t*3+r]=oi[r]; }
      }
    }
    __syncthreads();
    if (t == 0){
      for (int k=0;k<3;k++){
        ws[OFF_TV + b*3 + k] = sv[k];
        ((int*)(ws + OFF_TI))[b*3 + k] = si[k];
      }
    }
  }
}

// ================= k_mlp2: dedup MLP hidden partials, k-split x4 =================
__global__ __launch_bounds__(256) void k_mlp2(const float* __restrict__ nc,
    const float* __restrict__ dd_w1, const float* __restrict__ ds_w1,
    float* __restrict__ ws, float* __restrict__ out){
  int blk = blockIdx.x, t = threadIdx.x;
  int b = blk >> 2, ks = blk & 3;
  __shared__ float ch[3*256];
  if (ks < 2){
    ch[t] = nc[b*512 + ks*256 + t];
    __syncthreads();
    float hd = 0.f, hs = 0.f;
    const float* wd = dd_w1 + (ks*256)*256 + t;
    const float* wq = ds_w1 + (ks*256)*256 + t;
    #pragma unroll 4
    for (int i=0;i<256;i++){
      float c = ch[i];
      hd = fmaf(c, wd[i*256], hd);
      hs = fmaf(c, wq[i*256], hs);
    }
    float* H = ws + OFF_HNC + ((ks*64 + b)*2)*256;
    H[t] = hd; H[256 + t] = hs;
  } else {
    int ks2 = ks - 2;
    const int* tip = (const int*)(ws + OFF_TI);
    int r0 = tip[b*3], r1 = tip[b*3+1], r2 = tip[b*3+2];
    ch[t]       = out[OUT_MEM + (size_t)r0*512 + ks2*256 + t];
    ch[256 + t] = out[OUT_MEM + (size_t)r1*512 + ks2*256 + t];
    ch[512 + t] = out[OUT_MEM + (size_t)r2*512 + ks2*256 + t];
    __syncthreads();
    float hd0=0,hd1=0,hd2=0,hs0=0,hs1=0,hs2=0;
    const float* wd = dd_w1 + (512 + ks2*256)*256 + t;
    const float* wq = ds_w1 + (512 + ks2*256)*256 + t;
    #pragma unroll 4
    for (int i=0;i<256;i++){
      float w0 = wd[i*256], w1 = wq[i*256];
      float c0 = ch[i], c1 = ch[256+i], c2 = ch[512+i];
      hd0=fmaf(c0,w0,hd0); hd1=fmaf(c1,w0,hd1); hd2=fmaf(c2,w0,hd2);
      hs0=fmaf(c0,w1,hs0); hs1=fmaf(c1,w1,hs1); hs2=fmaf(c2,w1,hs2);
    }
    float* H = ws + OFF_HG;
    int p0 = b*3;
    H[((ks2*192 + p0+0)*2+0)*256 + t] = hd0;
    H[((ks2*192 + p0+1)*2+0)*256 + t] = hd1;
    H[((ks2*192 + p0+2)*2+0)*256 + t] = hd2;
    H[((ks2*192 + p0+0)*2+1)*256 + t] = hs0;
    H[((ks2*192 + p0+1)*2+1)*256 + t] = hs1;
    H[((ks2*192 + p0+2)*2+1)*256 + t] = hs2;
  }
}

// ================= k_pairfin: combine partials, decide apply, emit candidates =================
__global__ __launch_bounds__(256) void k_pairfin(const float* __restrict__ nc,
    const float* __restrict__ dd_b1, const float* __restrict__ dd_w2, const float* __restrict__ dd_b2,
    const float* __restrict__ ds_b1, const float* __restrict__ ds_w2, const float* __restrict__ ds_b2,
    float* __restrict__ ws, float* __restrict__ out){
  int p = blockIdx.x, t = threadIdx.x;
  int b = p / 3, k = p - 3*b;
  const int* tip = (const int*)(ws + OFF_TI);
  int row = tip[p];
  float hd = ws[OFF_HNC + ((0*64+b)*2+0)*256 + t] + ws[OFF_HNC + ((1*64+b)*2+0)*256 + t]
           + ws[OFF_HG + ((0*192+p)*2+0)*256 + t] + ws[OFF_HG + ((1*192+p)*2+0)*256 + t] + dd_b1[t];
  float hs = ws[OFF_HNC + ((0*64+b)*2+1)*256 + t] + ws[OFF_HNC + ((1*64+b)*2+1)*256 + t]
           + ws[OFF_HG + ((0*192+p)*2+1)*256 + t] + ws[OFF_HG + ((1*192+p)*2+1)*256 + t] + ds_b1[t];
  __shared__ float red[256];
  __shared__ float bc[2];
  red[t] = fmaxf(hd, 0.f) * dd_w2[t];
  __syncthreads();
  for (int o=128;o>0;o>>=1){ if (t<o) red[t]+=red[t+o]; __syncthreads(); }
  if (t == 0) bc[0] = red[0] + dd_b2[0];
  __syncthreads();
  red[t] = fmaxf(hs, 0.f) * ds_w2[t];
  __syncthreads();
  for (int o=128;o>0;o>>=1){ if (t<o) red[t]+=red[t+o]; __syncthreads(); }
  if (t == 0) bc[1] = red[0] + ds_b2[0];
  __syncthreads();
  float prob  = sigmoidf_(bc[0]);
  float stren = sigmoidf_(bc[1]);
  float tvv = ws[OFF_TV + p];
  int ap = (tvv > 0.7f && tvv < 0.99f && prob > 0.5f) ? 1 : 0;
  if (t == 0){
    ((int*)(ws + OFF_APPLY))[p] = ap;
    touch_row(row, ws);
  }
  for (int d=t; d<512; d+=256){
    float n = nc[b*512 + d];
    float g = out[OUT_MEM + (size_t)row*512 + d];
    float avg = 0.5f*(n + g);
    ws[OFF_DOCAND + p*512 + d] = (1.0f - stren)*g + stren*avg;
    if (b == 0) ws[OFF_DNC0 + k*512 + d] = (1.0f - stren)*n + stren*avg;
  }
}

// ================= k_scer: scatter (blk 0..1) + erase (blk 2..129) =================
__global__ __launch_bounds__(256) void k_scer(const int* __restrict__ step_p,
    const float* __restrict__ el_w, const float* __restrict__ el_b,
    const float* __restrict__ eg_w, const float* __restrict__ eg_b,
    float* __restrict__ ws, float* __restrict__ out){
  int blk = blockIdx.x, t = threadIdx.x;
  Scal* sc = (Scal*)(ws + OFF_SCAL);
  __shared__ unsigned long long rm[256], rs[256];
  if (blk < 2){
    // ---- scatter: columns independent; batch order serialized per column ----
    int d = blk*256 + t;   // 512 columns
    const int* tip = (const int*)(ws + OFF_TI);
    const int* ap  = (const int*)(ws + OFF_APPLY);
    for (int k=0;k<3;k++){
      float cur[64];
      #pragma unroll
      for (int b=0;b<64;b++) cur[b] = out[OUT_MEM + (size_t)tip[b*3 + k]*512 + d];
      #pragma unroll
      for (int b=0;b<64;b++){
        int p = b*3 + k;
        float v = ap[p] ? ws[OFF_DOCAND + p*512 + d] : cur[b];
        out[OUT_MEM + (size_t)tip[p]*512 + d] = v;
      }
    }
    return;
  }
  // ---- erase (128 blocks) ----
  float stepf = (float)step_p[0];
  float egb = eg_b[0];
  int gid = (blk-2)*256 + t;
  int gstride = 128*256;
  unsigned long long bm = 0ULL, bs = 0ULL;
  for (int s = gid; s < S_N; s += gstride){
    float a = out[OUT_AT + s];
    float x = (stepf - a) / 1000.0f;
    float lp = 0.0f;
    #pragma unroll
    for (int j=0;j<32;j++) lp += fmaxf(x*el_w[j] + el_b[j], 0.0f) * eg_w[j];
    float er = sigmoidf_(lp + ws[OFF_CONF + s] + egb);
    float sa = stepf - a;
    bool recent = (a >= 0.0f) && (sa < 3.0f);
    float msk = recent ? 0.0f : er;
    ws[OFF_ERSC + s] = er;
    ws[OFF_MASKED + s] = msk;
    ws[OFF_SLOTAGE + s] = sa;
    unsigned long long pm = packvi(msk, s); if (pm > bm) bm = pm;
    unsigned long long ps = packvi(sa,  s); if (ps > bs) bs = ps;
  }
  rm[t]=bm; rs[t]=bs; __syncthreads();
  for (int o=128;o>0;o>>=1){
    if (t<o){ if (rm[t+o]>rm[t]) rm[t]=rm[t+o]; if (rs[t+o]>rs[t]) rs[t]=rs[t+o]; }
    __syncthreads();
  }
  if (t == 0){
    atomicMax(&sc->masked_pack, rm[0]);
    atomicMax(&sc->slotage_pack, rs[0]);
  }
}

// ================= k_finalout: decide-logic recomputed per block =================
__global__ __launch_bounds__(256) void k_finalout(const float* __restrict__ nc,
                                                  const int* __restrict__ step_p,
                                                  float* __restrict__ ws, float* __restrict__ out){
  int blk = blockIdx.x, t = threadIdx.x;
  Scal* sc = (Scal*)(ws + OFF_SCAL);
  __shared__ float red[64];
  __shared__ int sh_ss, sh_wi;
  if (t < 64) red[t] = ws[OFF_STORES + t];
  __syncthreads();
  for (int o=32;o>0;o>>=1){ if (t<o) red[t]+=red[t+o]; __syncthreads(); }
  if (t == 0){
    float store_mean = red[0] / 64.0f;
    int cnt = sc->cnt_active;
    float capacity = (float)cnt / 65536.0f;
    float dyn_thr;
    if (capacity < 0.3f) dyn_thr = 0.08f;
    else if (capacity < 0.6f) dyn_thr = 0.08f + (capacity - 0.3f)*0.733f;
    else dyn_thr = 0.3f + (capacity - 0.6f);
    dyn_thr = fminf(fmaxf(dyn_thr, 0.0f), 0.7f);
    float topk_thr = (capacity < 0.3f) ? 0.1f : ((capacity < 0.6f) ? 0.2f : 0.4f);
    float raw_thr  = (capacity < 0.3f) ? 0.3f : 0.5f;
    int base_store = store_mean > raw_thr;
    int novelty_ok = sc->nov_mean > dyn_thr;
    int cmax = cnt > 1 ? cnt : 1;
    float denom = (float)(64 * cmax);
    float perc = (cnt > 0) ? ((float)sc->cond_cnt) / denom : 1.0f;
    int topk_ok = perc > topk_thr;
    int de = sc->do_erase;
    int ss = base_store && novelty_ok && topk_ok;
    if (de && !novelty_ok) ss = 0;
    float mmax = mono2f((unsigned)(sc->masked_pack >> 32));
    int marg = (int)(0xFFFFFFFFu - (unsigned)(sc->masked_pack  & 0xFFFFFFFFULL));
    int sarg = (int)(0xFFFFFFFFu - (unsigned)(sc->slotage_pack & 0xFFFFFFFFULL));
    sh_ss = ss;
    sh_wi = de ? sc->victim_idx : ((mmax > 0.0f) ? marg : sarg);
  }
  __syncthreads();
  int ss = sh_ss, de = sc->do_erase;
  if (blk == 64){
    if (ss){
      int wi = sh_wi;
      const int* ap = (const int*)(ws + OFF_APPLY);
      for (int d=t; d<512; d+=256){
        float v = nc[d];               // b = 0 row
        if (ap[0]) v = ws[OFF_DNC0 + 0*512 + d];
        if (ap[1]) v = ws[OFF_DNC0 + 1*512 + d];
        if (ap[2]) v = ws[OFF_DNC0 + 2*512 + d];
        out[OUT_MEM + (size_t)wi*512 + d] = v;
      }
      if (t == 0){
        out[OUT_AT + wi] = (float)step_p[0];
        touch_row(wi, ws);
      }
    }
    return;
  }
  float mmax = mono2f((unsigned)(sc->masked_pack >> 32));
  bool usemask = ss && !de;
  for (int s = blk*256 + t; s < S_N; s += 64*256){
    float v;
    if (usemask) v = (mmax <= 0.0f) ? ws[OFF_SLOTAGE + s] : ws[OFF_MASKED + s];
    else v = ws[OFF_ERSC + s];
    out[OUT_ER + s] = v;
  }
}

// ================= k_diff: |out_mem - mem| over touched rows; rc folded in =================
__global__ __launch_bounds__(256) void k_diff(const float* __restrict__ mem,
                                              float* __restrict__ ws, float* __restrict__ out){
  int t = threadIdx.x;
  Scal* sc = (Scal*)(ws + OFF_SCAL);
  int cnt = sc->list_cnt;
  const int* list = (const int*)(ws + OFF_LIST);
  float lsum = 0.0f;
  for (int i = blockIdx.x; i < cnt; i += gridDim.x){
    int row = list[i];
    float part = 0.0f;
    for (int d=t; d<512; d+=256)
      part += fabsf(out[OUT_MEM + (size_t)row*512 + d] - mem[(size_t)row*512 + d]);
    lsum += part;
  }
  __shared__ float red[256];
  red[t] = lsum; __syncthreads();
  for (int o=128;o>0;o>>=1){ if (t<o) red[t]+=red[t+o]; __syncthreads(); }
  if (t == 0 && red[0] != 0.0f) atomicAdd(out + OUT_RC, red[0] * (1.0f/33554432.0f));
}

// ================= host =================
extern "C" void kernel_launch(void* const* d_in, const int* in_sizes, int n_in,
                              void* d_out, int out_size, void* d_ws, size_t ws_size,
                              hipStream_t stream) {
  const float* nc    = (const float*)d_in[0];
  const float* qr    = (const float*)d_in[1];
  const float* mem   = (const float*)d_in[2];
  const float* at    = (const float*)d_in[3];
  const int*   step  = (const int*)  d_in[4];
  const float* sr_w1 = (const float*)d_in[5];
  const float* sr_b1 = (const float*)d_in[6];
  const float* sr_g  = (const float*)d_in[7];
  const float* sr_be = (const float*)d_in[8];
  const float* sr_w2 = (const float*)d_in[9];
  const float* sr_b2 = (const float*)d_in[10];
  const float* sn_w  = (const float*)d_in[11];
  const float* sn_b  = (const float*)d_in[12];
  const float* sg_w  = (const float*)d_in[13];
  const float* sg_b  = (const float*)d_in[14];
  const float* el_w  = (const float*)d_in[15];
  const float* el_b  = (const float*)d_in[16];
  const float* ec_w  = (const float*)d_in[17];
  const float* ec_b  = (const float*)d_in[18];
  const float* eg_w  = (const float*)d_in[19];
  const float* eg_b  = (const float*)d_in[20];
  const float* dd_w1 = (const float*)d_in[21];
  const float* dd_b1 = (const float*)d_in[22];
  const float* dd_w2 = (const float*)d_in[23];
  const float* dd_b2 = (const float*)d_in[24];
  const float* ds_w1 = (const float*)d_in[25];
  const float* ds_b1 = (const float*)d_in[26];
  const float* ds_w2 = (const float*)d_in[27];
  const float* ds_b2 = (const float*)d_in[28];
  float* out = (float*)d_out;
  float* ws  = (float*)d_ws;

  k_initm    <<<dim3(1057), dim3(256), 0, stream>>>(nc, qr, at, ec_w, step, sr_w1, sn_w, ws, out);
  k_phase1   <<<dim3(512), dim3(256), 0, stream>>>(mem, ec_b, eg_w, ws, out, 0);
  k_phase1   <<<dim3(512), dim3(256), 0, stream>>>(mem, ec_b, eg_w, ws, out, 512);
  k_victim   <<<dim3(64), dim3(256), 0, stream>>>(at, step, ws);
  k_mid      <<<dim3(642), dim3(256), 0, stream>>>(nc, qr, sr_b1, sr_g, sr_be,
                                                   sr_w2, sr_b2, sn_b, sg_w, sg_b,
                                                   ec_b, eg_w, ws, out);
  k_mlp2     <<<dim3(256), dim3(256), 0, stream>>>(nc, dd_w1, ds_w1, ws, out);
  k_pairfin  <<<dim3(192), dim3(256), 0, stream>>>(nc, dd_b1, dd_w2, dd_b2,
                                                   ds_b1, ds_w2, ds_b2, ws, out);
  k_scer     <<<dim3(130), dim3(256), 0, stream>>>(step, el_w, el_b, eg_w, eg_b, ws, out);
  k_finalout <<<dim3(65), dim3(256), 0, stream>>>(nc, step, ws, out);
  k_diff     <<<dim3(64), dim3(256), 0, stream>>>(mem, ws, out);
}

// Round 8
// 471.196 us; speedup vs baseline: 1.0714x; 1.0070x over previous
//
#include <hip/hip_runtime.h>
#include <math.h>
#include <limits.h>

#define S_N 65536
#define D_N 512
#define B_N 64

typedef __attribute__((ext_vector_type(8))) short short8;
typedef __attribute__((ext_vector_type(4))) float f32x4;

// ---------------- workspace layout (float indices) ----------------
#define SIMS_F      (B_N*S_N/2)                 // bf16 sims stored as ushort
#define OFF_SIMS    0
#define OFF_AEXT    (OFF_SIMS + SIMS_F)         // ushort[96*512]: rows 0..63 norm(nc), 64..95 ec_w^T (bf16)
#define AEXT_F      (96*512/2)
#define OFF_NORMS   (OFF_AEXT + AEXT_F)
#define OFF_CONF    (OFF_NORMS + S_N)
#define OFF_FLAGS   (OFF_CONF + S_N)            // int
#define OFF_LIST    (OFF_FLAGS + S_N)           // int[256] touched rows
#define OFF_MASKED  (OFF_LIST + 256)
#define OFF_ERSC    (OFF_MASKED + S_N)
#define OFF_SLOTAGE (OFF_ERSC + S_N)
#define OFF_STORES  (OFF_SLOTAGE + S_N)         // 64
#define OFF_MAXSIM  (OFF_STORES + 64)           // 64 u32 mono
#define OFF_TI      (OFF_MAXSIM + 64)           // 192 int
#define OFF_TV      (OFF_TI + 192)              // 192
#define OFF_APPLY   (OFF_TV + 192)              // 192 int
#define OFF_HM      (OFF_APPLY + 192)           // mlp1 partials [8][64][256] (spills into HNC/HG space;
                                                //   safe: initm writes, k_mid reads, then k_mlp2 overwrites)
#define OFF_HNC     (OFF_HM + 32768)            // 2*64*2*256 mlp2 nc-half partials
#define OFF_HG      (OFF_HNC + 65536)           // 2*192*2*256 mlp2 gathered-half partials
#define OFF_DNC0    (OFF_HG + 196608)           // 3*512
#define OFF_DRIFT0  (OFF_DNC0 + 1536)           // 512
#define OFF_DOCAND  (OFF_DRIFT0 + 512)          // 192*512
#define OFF_SNP     OFF_DOCAND                  // [4][64][2][128] nf partials (initm writes, mlp1b reads,
                                                //   only then pairfin overwrites DOCAND)
#define OFF_SCAL    (OFF_DOCAND + 98304)

// ---------------- output layout (floats) ----------------
#define OUT_MEM 0
#define OUT_AT  (S_N*D_N)
#define OUT_ER  (OUT_AT + S_N)
#define OUT_SS  (OUT_ER + S_N)
#define OUT_NOV (OUT_SS + 64)
#define OUT_RC  (OUT_NOV + 64)

struct __align__(8) Scal {
  unsigned long long victim_pack;
  unsigned long long masked_pack;
  unsigned long long slotage_pack;
  int cnt_active;
  int cond_cnt;
  unsigned age_max_t;
  float nov_mean;
  float changed_sum;
  int do_erase;
  int should_store;
  int write_idx;
  int victim_idx;
  int list_cnt;
};

__device__ __forceinline__ float sigmoidf_(float x){ return 1.0f/(1.0f+expf(-x)); }
__device__ __forceinline__ unsigned f2mono(float f){
  unsigned u = __float_as_uint(f);
  return (u & 0x80000000u) ? ~u : (u | 0x80000000u);
}
__device__ __forceinline__ float mono2f(unsigned m){
  unsigned u = (m & 0x80000000u) ? (m & 0x7FFFFFFFu) : ~m;
  return __uint_as_float(u);
}
__device__ __forceinline__ unsigned long long packvi(float v, int i){
  return (((unsigned long long)f2mono(v)) << 32) | (unsigned long long)(0xFFFFFFFFu - (unsigned)i);
}
__device__ __forceinline__ bool betterVI(float v, int i, float v2, int i2){
  return (v > v2) || (v == v2 && i < i2);
}
__device__ __forceinline__ unsigned short bf16r(float f){   // RNE f32->bf16
  unsigned u = __float_as_uint(f);
  return (unsigned short)((u + 0x7fffu + ((u>>16)&1u)) >> 16);
}
__device__ __forceinline__ float bf2f(unsigned short h){
  return __uint_as_float(((unsigned)h)<<16);
}
__device__ __forceinline__ void touch_row(int row, float* ws){
  int* flags = (int*)(ws + OFF_FLAGS);
  if (atomicExch(&flags[row], 1) == 0){
    Scal* sc = (Scal*)(ws + OFF_SCAL);
    int i = atomicAdd(&sc->list_cnt, 1);
    ((int*)(ws + OFF_LIST))[i] = row;
  }
}

// async global->LDS, 16B per lane. dest = wave-uniform base + lane*16; src per-lane.
__device__ __forceinline__ void gld16(const float* g, void* l){
  __builtin_amdgcn_global_load_lds((const __attribute__((address_space(1))) void*)g,
                                   (__attribute__((address_space(3))) void*)l, 16, 0, 0);
}
#define WAITV(N) asm volatile("s_waitcnt vmcnt(" #N ")" ::: "memory")

// ================= k_initm: init (289) + mlp1a ksplit8 (512) + nf partials (256) =================
__global__ __launch_bounds__(256) void k_initm(const float* __restrict__ nc,
                                               const float* __restrict__ qr,
                                               const float* __restrict__ at_in,
                                               const float* __restrict__ ec_w,
                                               const int* __restrict__ step_p,
                                               const float* __restrict__ sr_w1,
                                               const float* __restrict__ sn_w,
                                               float* __restrict__ ws, float* __restrict__ out){
  int blk = blockIdx.x, t = threadIdx.x;
  Scal* sc = (Scal*)(ws + OFF_SCAL);
  unsigned short* aB = (unsigned short*)(ws + OFF_AEXT);
  __shared__ float red[256];
  __shared__ float ch[256];
  if (blk == 0){
    if (t == 0){
      sc->victim_pack = 0ULL; sc->masked_pack = 0ULL; sc->slotage_pack = 0ULL;
      sc->cnt_active = 0; sc->cond_cnt = 0; sc->age_max_t = 0u;
      sc->nov_mean = 0.0f; sc->changed_sum = 0.0f;
      sc->do_erase = 0; sc->should_store = 0; sc->write_idx = 0; sc->victim_idx = 0;
      sc->list_cnt = 0;
      out[OUT_RC] = 0.0f;           // k_diff atomicAdds into this
    }
    if (t < 64) ((unsigned*)(ws + OFF_MAXSIM))[t] = 0u;
  } else if (blk <= 64){
    int b = blk - 1;
    float x0 = nc[b*512 + t], x1 = nc[b*512 + 256 + t];
    red[t] = x0*x0 + x1*x1;
    __syncthreads();
    for (int o=128;o>0;o>>=1){ if (t<o) red[t]+=red[t+o]; __syncthreads(); }
    float inv = 1.0f / fmaxf(sqrtf(red[0]), 1e-12f);
    aB[b*512 + t]       = bf16r(x0*inv);
    aB[b*512 + 256 + t] = bf16r(x1*inv);
  } else if (blk <= 96){
    int j = blk - 65;
    for (int d=t; d<512; d+=256) aB[(64+j)*512 + d] = bf16r(ec_w[d*32 + j]);
  } else if (blk <= 160){
    int part = blk - 97;
    float stepf = (float)step_p[0];
    float lmaxv = -1e30f;
    for (int s = part*1024 + t; s < (part+1)*1024; s += 256)
      lmaxv = fmaxf(lmaxv, fmaxf(stepf - at_in[s], 0.0f));
    red[t]=lmaxv; __syncthreads();
    for (int o=128;o>0;o>>=1){ if (t<o) red[t]=fmaxf(red[t],red[t+o]); __syncthreads(); }
    if (t==0) atomicMax(&sc->age_max_t, f2mono(red[0]));
  } else if (blk <= 224){
    int part = blk - 161;
    for (int s = part*1024 + t; s < (part+1)*1024; s += 256)
      out[OUT_AT + s] = at_in[s];
  } else if (blk <= 288){
    int part = blk - 225;   // 64 parts
    int* flags = (int*)(ws + OFF_FLAGS);
    for (int s = part*1024 + t; s < (part+1)*1024; s += 256) flags[s] = 0;
  } else if (blk <= 800){
    // ---- mlp1a: h partials, k-split 8 (512 blocks, 128-iter loops) ----
    int blk2 = blk - 289;             // 0..511
    int b = blk2 >> 3, s = blk2 & 7;
    const float* src = (s < 4) ? nc : qr;
    if (t < 128) ch[t] = src[b*512 + (s & 3)*128 + t];
    __syncthreads();
    float h = 0.f;
    const float* w = sr_w1 + (s*128)*256 + t;
    #pragma unroll 8
    for (int i=0;i<128;i++) h = fmaf(ch[i], w[i*256], h);
    ws[OFF_HM + (s*64 + b)*256 + t] = h;
  } else {
    // ---- nf (sn_w) partials: [ks 0..3][b][kh 0..1][128], 64-iter loops, all 256 threads ----
    int blk2 = blk - 801;             // 0..255
    int b = blk2 >> 2, ks = blk2 & 3;
    int o = t & 127, kh = t >> 7;
    if (t < 128) ch[t] = nc[b*512 + ks*128 + t];
    __syncthreads();
    float p = 0.f;
    const float* w = sn_w + (ks*128 + kh*64)*128 + o;
    #pragma unroll 8
    for (int i=0;i<64;i++) p = fmaf(ch[kh*64 + i], w[i*128], p);
    ws[OFF_SNP + ((ks*64 + b)*2 + kh)*128 + o] = p;
  }
}

// ================= k_phase1 v6: 8-wave / 128-row geometry, CLEAN (no victim fold, no
// extra pointer args — R3/R4's regressions are attributed to loop-invariant epilogue
// loads hoisted into the K-loop preheader, corrupting the counted-vmcnt FIFO).
// Inner loop/waits = verified FIFO math: ring-3, depth-2, waits 4,6,8..8,6,4.
// 2 waves/SIMD fill DMA-issue gaps during consume; 32 KB in flight/CU.
__global__ __launch_bounds__(512) void k_phase1(const float* __restrict__ mem,
                                                const float* __restrict__ ec_b,
                                                const float* __restrict__ eg_w,
                                                float* __restrict__ ws, float* __restrict__ out,
                                                int s_base){
  __shared__ __align__(16) unsigned short aT[96*520];   // 99,840 B, padded rows
  __shared__ __align__(16) char chunks[8*3*2048];       // 49,152 B: 8 waves x 3 bufs
  __shared__ unsigned lmax[64];
  int t = threadIdx.x;
  int s0 = (blockIdx.x + s_base) * 128;
  Scal* sc = (Scal*)(ws + OFF_SCAL);
  int lane = t & 63, wv = t >> 6;        // wv 0..7
  int quad = lane >> 4, l15 = lane & 15;
  int row = wv*16 + l15;                 // 0..127: mem row this lane consumes == its sims column

  // ---- stage Aext (bf16) global ws -> padded LDS; 6144 uint4, 12/thread ----
  {
    const uint4* src = (const uint4*)(ws + OFF_AEXT);
    #pragma unroll
    for (int i=0;i<12;i++){
      int idx = i*512 + t;
      int arow = idx >> 6, c16 = idx & 63;
      uint4 v = src[idx];
      *(uint4*)((char*)aT + arow*1040 + c16*16) = v;
    }
    if (t < 64) lmax[t] = 0u;
  }
  __syncthreads();   // drains vmcnt/lgkmcnt -> clean FIFO for counted waits below

  const float* gsrc = mem + ((size_t)(s0 + row))*512 + quad*8;
  float* od = out + OUT_MEM + ((size_t)(s0 + row))*512 + quad*8;
  char* mybuf = chunks + wv*6144;
  #define STAGE(c) do{ \
    gld16(gsrc + (c)*32,     mybuf + ((c)%3)*2048); \
    gld16(gsrc + (c)*32 + 4, mybuf + ((c)%3)*2048 + 1024); \
  }while(0)

  STAGE(0); asm volatile("" ::: "memory");
  STAGE(1); asm volatile("" ::: "memory");

  f32x4 acc[6];
  #pragma unroll
  for (int r=0;r<6;r++) acc[r] = (f32x4){0.f,0.f,0.f,0.f};
  float ssq = 0.f;

  #pragma unroll
  for (int c=0;c<16;c++){
    if (c < 14) STAGE(c+2);
    // counted waits (4 vmcnt ops/iter: 2 stage loads + 2 copy-out stores), FIFO-derived:
    // c=0: 6 in FIFO, need L0 done -> leave 4. c=1: leave 6. steady: leave 8. tail: 6,4.
    if      (c == 0)  WAITV(4);
    else if (c == 1)  WAITV(6);
    else if (c <= 13) WAITV(8);
    else if (c == 14) WAITV(6);
    else              WAITV(4);
    __builtin_amdgcn_sched_barrier(0);
    const char* bp = mybuf + (c%3)*2048;
    float4 v0 = *(const float4*)(bp + lane*16);
    float4 v1 = *(const float4*)(bp + 1024 + lane*16);
    *(float4*)(od + c*32)     = v0;     // copy-out fused (2 stores/iter, counted above)
    *(float4*)(od + c*32 + 4) = v1;
    ssq = fmaf(v0.x,v0.x,ssq); ssq = fmaf(v0.y,v0.y,ssq);
    ssq = fmaf(v0.z,v0.z,ssq); ssq = fmaf(v0.w,v0.w,ssq);
    ssq = fmaf(v1.x,v1.x,ssq); ssq = fmaf(v1.y,v1.y,ssq);
    ssq = fmaf(v1.z,v1.z,ssq); ssq = fmaf(v1.w,v1.w,ssq);
    short8 bfrag;
    bfrag[0]=(short)bf16r(v0.x); bfrag[1]=(short)bf16r(v0.y);
    bfrag[2]=(short)bf16r(v0.z); bfrag[3]=(short)bf16r(v0.w);
    bfrag[4]=(short)bf16r(v1.x); bfrag[5]=(short)bf16r(v1.y);
    bfrag[6]=(short)bf16r(v1.z); bfrag[7]=(short)bf16r(v1.w);
    #pragma unroll
    for (int rt=0;rt<6;rt++){
      short8 afrag = *(const short8*)((const char*)aT + (rt*16 + l15)*1040 + c*64 + quad*16);
      acc[rt] = __builtin_amdgcn_mfma_f32_16x16x32_bf16(afrag, bfrag, acc[rt], 0,0,0);
    }
  }
  #undef STAGE

  // ---- row norm: quads hold disjoint col-chunks of the same row ----
  ssq += __shfl_xor(ssq, 16);
  ssq += __shfl_xor(ssq, 32);
  float nrm = sqrtf(ssq);
  float lv = 1.0f / fmaxf(nrm, 1e-12f);
  if (quad == 0) ws[OFF_NORMS + s0 + row] = nrm;
  unsigned long long m = __ballot(quad==0 && nrm > 0.5f);
  if (lane == 0) atomicAdd(&sc->cnt_active, (int)__popcll(m));

  // ---- epilogue: D[a][s] col=l15(+wv*16+s0), row=quad*4+reg ----
  unsigned short* simsb = (unsigned short*)(ws + OFF_SIMS);
  #pragma unroll
  for (int rt=0;rt<4;rt++){
    #pragma unroll
    for (int r=0;r<4;r++){
      int a = rt*16 + quad*4 + r;
      float sim = acc[rt][r] * lv;
      simsb[(size_t)a*S_N + s0 + row] = bf16r(sim);
      atomicMax(&lmax[a], f2mono(sim));
    }
  }
  float cpart = 0.f;
  #pragma unroll
  for (int rt=4;rt<6;rt++){
    #pragma unroll
    for (int r=0;r<4;r++){
      int j = (rt-4)*16 + quad*4 + r;
      cpart += sigmoidf_(acc[rt][r] + ec_b[j]) * eg_w[32+j];
    }
  }
  cpart += __shfl_down(cpart, 32);
  cpart += __shfl_down(cpart, 16);
  if (lane < 16) ws[OFF_CONF + s0 + row] = cpart;
  __syncthreads();
  if (t < 64) atomicMax(((unsigned*)(ws + OFF_MAXSIM)) + t, lmax[t]);
}

// ================= k_victim: es argmax (separate kernel so phase1 codegen stays clean) =================
__global__ __launch_bounds__(256) void k_victim(const float* __restrict__ at_in,
                                                const int* __restrict__ step_p,
                                                float* __restrict__ ws){
  int t = threadIdx.x;
  Scal* sc = (Scal*)(ws + OFF_SCAL);
  float stepf = (float)step_p[0];
  float agemax = mono2f(sc->age_max_t);
  const float* norms = ws + OFF_NORMS;
  int gid = blockIdx.x*256 + t;
  int gstride = gridDim.x*256;
  unsigned long long best = 0ULL;
  for (int s = gid; s < S_N; s += gstride){
    float age = fmaxf(stepf - at_in[s], 0.0f);
    float es = age/(agemax + 1e-6f) + (1.0f - sigmoidf_(norms[s]));
    unsigned long long pk = packvi(es, s);
    if (pk > best) best = pk;
  }
  __shared__ unsigned long long redp[256];
  redp[t] = best; __syncthreads();
  for (int o=128;o>0;o>>=1){
    if (t<o && redp[t+o] > redp[t]) redp[t] = redp[t+o];
    __syncthreads();
  }
  if (t == 0) atomicMax(&sc->victim_pack, redp[0]);
}

// ================= k_mid: mlp1b(0..64) + victimfix(65) + cond-scan(66..577) + top3(578..641) =================
__global__ __launch_bounds__(256) void k_mid(const float* __restrict__ nc, const float* __restrict__ qr,
    const float* __restrict__ sr_b1, const float* __restrict__ sr_g, const float* __restrict__ sr_beta,
    const float* __restrict__ sr_w2, const float* __restrict__ sr_b2,
    const float* __restrict__ sn_b,
    const float* __restrict__ sg_w,  const float* __restrict__ sg_b,
    const float* __restrict__ ec_b,  const float* __restrict__ eg_w,
    float* __restrict__ ws, float* __restrict__ out){
  int blk = blockIdx.x, t = threadIdx.x;
  Scal* sc = (Scal*)(ws + OFF_SCAL);
  __shared__ float red[256];
  __shared__ float hbuf[256];
  __shared__ float sv[256*3];
  __shared__ int   si[256*3];

  if (blk == 64){
    // novelty outputs + sc->nov_mean (for decide logic later)
    const unsigned* gms = (const unsigned*)(ws + OFF_MAXSIM);
    float nv = 0.0f;
    if (t < 64){
      float msim = mono2f(gms[t]);
      nv = (1.0f - msim) * 0.5f;
      out[OUT_NOV + t] = nv;
    }
    red[t] = (t < 64) ? nv : 0.0f;
    __syncthreads();
    for (int o=128;o>0;o>>=1){ if (t<o) red[t]+=red[t+o]; __syncthreads(); }
    if (t == 0) sc->nov_mean = red[0] / 64.0f;
    return;
  }
  if (blk < 64){
    // ---- mlp1b: sum 8 h-partials, LN, split r-dot, nf from partials, store gate ----
    int b = blk;
    float h = sr_b1[t];
    #pragma unroll
    for (int s=0;s<8;s++) h += ws[OFF_HM + (s*64 + b)*256 + t];
    red[t] = h; __syncthreads();
    for (int o=128;o>0;o>>=1){ if (t<o) red[t]+=red[t+o]; __syncthreads(); }
    float mean = red[0] / 256.0f;
    __syncthreads();
    float dx = h - mean;
    red[t] = dx*dx; __syncthreads();
    for (int o=128;o>0;o>>=1){ if (t<o) red[t]+=red[t+o]; __syncthreads(); }
    float var = red[0] / 256.0f;
    __syncthreads();
    float hn = dx / sqrtf(var + 1e-5f) * sr_g[t] + sr_beta[t];
    hbuf[t] = fmaxf(hn, 0.0f);
    __syncthreads();
    // r partial: all 256 threads; output o = t&127, j-half jh = t>>7
    int oo = t & 127, jh = t >> 7;
    float rp = 0.f;
    const float* w2 = sr_w2 + (jh*128)*128 + oo;
    #pragma unroll 8
    for (int j=0;j<128;j++) rp = fmaf(hbuf[jh*128 + j], w2[j*128], rp);
    red[t] = rp;
    __syncthreads();
    float val = 0.0f;
    if (t < 128){
      float r = fmaxf(red[t] + red[t+128] + sr_b2[t], 0.0f);
      float nfl = sn_b[t];
      #pragma unroll
      for (int q=0;q<8;q++) nfl += ws[OFF_SNP + (((q>>1)*64 + b)*2 + (q&1))*128 + t];
      float nf = sigmoidf_(nfl);
      val = (r + nf) * sg_w[t];
    }
    __syncthreads();
    red[t] = val;                  // t>=128 contribute 0
    __syncthreads();
    for (int o=128;o>0;o>>=1){ if (t<o) red[t]+=red[t+o]; __syncthreads(); }
    if (t == 0){
      float ssc = sigmoidf_(red[0] + sg_b[0]);
      out[OUT_SS + b] = ssc;
      ws[OFF_STORES + b] = ssc;
    }
    return;
  }
  if (blk == 65){
    // ---- victimfix ----
    float capacity = (float)sc->cnt_active / 65536.0f;
    int de = (capacity > 0.85f) ? 1 : 0;
    int victim = (int)(0xFFFFFFFFu - (unsigned)(sc->victim_pack & 0xFFFFFFFFULL));
    if (t == 0){ sc->do_erase = de; sc->victim_idx = victim; }
    if (de){
      for (int d=t; d<512; d+=256) out[OUT_MEM + victim*512 + d] = 0.0f;
      if (t == 0){
        out[OUT_AT + victim] = -99999.0f;
        touch_row(victim, ws);
        float sum = 0.0f;
        for (int j=0;j<32;j++) sum += sigmoidf_(ec_b[j]) * eg_w[32 + j];
        ws[OFF_CONF + victim] = sum;
      }
    }
    return;
  }
  if (blk < 578){
    // ---- cond count (uint4 = 8 sims/iter); nov_mean re-reduced locally ----
    const unsigned* gms = (const unsigned*)(ws + OFF_MAXSIM);
    red[t] = (t < 64) ? (1.0f - mono2f(gms[t])) * 0.5f : 0.0f;
    __syncthreads();
    for (int o=128;o>0;o>>=1){ if (t<o) red[t]+=red[t+o]; __syncthreads(); }
    float thr = 1.0f - red[0] / 64.0f;
    const uint4* sims4 = (const uint4*)(ws + OFF_SIMS);
    const float* norms = ws + OFF_NORMS;
    int gid = (blk - 66)*256 + t;
    int gstride = 512*256;
    int cnt = 0;
    for (int idx = gid; idx < B_N*S_N/8; idx += gstride){
      uint4 u = sims4[idx];
      int s = (idx*8) & (S_N-1);
      const float4* n4 = (const float4*)(norms + s);
      float4 na = n4[0], nb = n4[1];
      if (__uint_as_float(u.x<<16)          > thr && na.x > 0.5f) cnt++;
      if (__uint_as_float(u.x & 0xffff0000u) > thr && na.y > 0.5f) cnt++;
      if (__uint_as_float(u.y<<16)          > thr && na.z > 0.5f) cnt++;
      if (__uint_as_float(u.y & 0xffff0000u) > thr && na.w > 0.5f) cnt++;
      if (__uint_as_float(u.z<<16)          > thr && nb.x > 0.5f) cnt++;
      if (__uint_as_float(u.z & 0xffff0000u) > thr && nb.y > 0.5f) cnt++;
      if (__uint_as_float(u.w<<16)          > thr && nb.z > 0.5f) cnt++;
      if (__uint_as_float(u.w & 0xffff0000u) > thr && nb.w > 0.5f) cnt++;
    }
    __syncthreads();
    int* redc = (int*)red;
    redc[t] = cnt;
    __syncthreads();
    for (int o=128;o>0;o>>=1){ if (t<o) redc[t]+=redc[t+o]; __syncthreads(); }
    if (t == 0) atomicAdd(&sc->cond_cnt, redc[0]);
    return;
  }
  // ---- top3 (uint2 = 4 sims/iter): b = blk - 578 ----
  {
    int b = blk - 578;
    int victim = (int)(0xFFFFFFFFu - (unsigned)(sc->victim_pack & 0xFFFFFFFFULL));
    int de = (((float)sc->cnt_active / 65536.0f) > 0.85f) ? 1 : 0;
    const uint2* simrow2 = (const uint2*)((const unsigned short*)(ws + OFF_SIMS) + (size_t)b*S_N);
    float v[3] = {-1e30f,-1e30f,-1e30f};
    int ix[3] = {INT_MAX, INT_MAX, INT_MAX};
    for (int q = t; q < S_N/4; q += 256){
      uint2 u = simrow2[q];
      int s = q*4;
      float vals[4];
      vals[0] = __uint_as_float(u.x<<16);
      vals[1] = __uint_as_float(u.x & 0xffff0000u);
      vals[2] = __uint_as_float(u.y<<16);
      vals[3] = __uint_as_float(u.y & 0xffff0000u);
      #pragma unroll
      for (int r4=0;r4<4;r4++){
        float val = vals[r4];
        int ss = s + r4;
        if (de && ss == victim) val = 0.0f;
        if (betterVI(val, ss, v[2], ix[2])){
          if (betterVI(val, ss, v[1], ix[1])){
            if (betterVI(val, ss, v[0], ix[0])){
              v[2]=v[1]; ix[2]=ix[1]; v[1]=v[0]; ix[1]=ix[0]; v[0]=val; ix[0]=ss;
            } else { v[2]=v[1]; ix[2]=ix[1]; v[1]=val; ix[1]=ss; }
          } else { v[2]=val; ix[2]=ss; }
        }
      }
    }
    for (int r=0;r<3;r++){ sv[t*3+r]=v[r]; si[t*3+r]=ix[r]; }
    for (int off=128; off>0; off>>=1){
      __syncthreads();
      if (t < off){
        float av[3], bv[3], ov[3]; int ai[3], bi[3], oi[3];
        for (int r=0;r<3;r++){ av[r]=sv[t*3+r]; ai[r]=si[t*3+r]; bv[r]=sv[(t+off)*3+r]; bi[r]=si[(t+off)*3+r]; }
        int ap=0, bp=0;
        for (int r=0;r<3;r++){
          bool takeA = (bp>=3) || (ap<3 && betterVI(av[ap],ai[ap],bv[bp],bi[bp]));
          if (takeA){ ov[r]=av[ap]; oi[r]=ai[ap]; ap++; }
          else      { ov[r]=bv[bp]; oi[r]=bi[bp]; bp++; }
        }
        for (int r=0;r<3;r++){ sv[t*3+r]=ov[r]; si[t*3+r]=oi[r]; }
      }
    }
    __syncthreads();
    if (t == 0){
      for (int k=0;k<3;k++){
        ws[OFF_TV + b*3 + k] = sv[k];
        ((int*)(ws + OFF_TI))[b*3 + k] = si[k];
      }
    }
  }
}

// ================= k_mlp2: dedup MLP hidden partials, k-split x4 =================
__global__ __launch_bounds__(256) void k_mlp2(const float* __restrict__ nc,
    const float* __restrict__ dd_w1, const float* __restrict__ ds_w1,
    float* __restrict__ ws, float* __restrict__ out){
  int blk = blockIdx.x, t = threadIdx.x;
  int b = blk >> 2, ks = blk & 3;
  __shared__ float ch[3*256];
  if (ks < 2){
    ch[t] = nc[b*512 + ks*256 + t];
    __syncthreads();
    float hd = 0.f, hs = 0.f;
    const float* wd = dd_w1 + (ks*256)*256 + t;
    const float* wq = ds_w1 + (ks*256)*256 + t;
    #pragma unroll 4
    for (int i=0;i<256;i++){
      float c = ch[i];
      hd = fmaf(c, wd[i*256], hd);
      hs = fmaf(c, wq[i*256], hs);
    }
    float* H = ws + OFF_HNC + ((ks*64 + b)*2)*256;
    H[t] = hd; H[256 + t] = hs;
  } else {
    int ks2 = ks - 2;
    const int* tip = (const int*)(ws + OFF_TI);
    int r0 = tip[b*3], r1 = tip[b*3+1], r2 = tip[b*3+2];
    ch[t]       = out[OUT_MEM + (size_t)r0*512 + ks2*256 + t];
    ch[256 + t] = out[OUT_MEM + (size_t)r1*512 + ks2*256 + t];
    ch[512 + t] = out[OUT_MEM + (size_t)r2*512 + ks2*256 + t];
    __syncthreads();
    float hd0=0,hd1=0,hd2=0,hs0=0,hs1=0,hs2=0;
    const float* wd = dd_w1 + (512 + ks2*256)*256 + t;
    const float* wq = ds_w1 + (512 + ks2*256)*256 + t;
    #pragma unroll 4
    for (int i=0;i<256;i++){
      float w0 = wd[i*256], w1 = wq[i*256];
      float c0 = ch[i], c1 = ch[256+i], c2 = ch[512+i];
      hd0=fmaf(c0,w0,hd0); hd1=fmaf(c1,w0,hd1); hd2=fmaf(c2,w0,hd2);
      hs0=fmaf(c0,w1,hs0); hs1=fmaf(c1,w1,hs1); hs2=fmaf(c2,w1,hs2);
    }
    float* H = ws + OFF_HG;
    int p0 = b*3;
    H[((ks2*192 + p0+0)*2+0)*256 + t] = hd0;
    H[((ks2*192 + p0+1)*2+0)*256 + t] = hd1;
    H[((ks2*192 + p0+2)*2+0)*256 + t] = hd2;
    H[((ks2*192 + p0+0)*2+1)*256 + t] = hs0;
    H[((ks2*192 + p0+1)*2+1)*256 + t] = hs1;
    H[((ks2*192 + p0+2)*2+1)*256 + t] = hs2;
  }
}

// ================= k_pairfin: combine partials, decide apply, emit candidates =================
__global__ __launch_bounds__(256) void k_pairfin(const float* __restrict__ nc,
    const float* __restrict__ dd_b1, const float* __restrict__ dd_w2, const float* __restrict__ dd_b2,
    const float* __restrict__ ds_b1, const float* __restrict__ ds_w2, const float* __restrict__ ds_b2,
    float* __restrict__ ws, float* __restrict__ out){
  int p = blockIdx.x, t = threadIdx.x;
  int b = p / 3, k = p - 3*b;
  const int* tip = (const int*)(ws + OFF_TI);
  int row = tip[p];
  float hd = ws[OFF_HNC + ((0*64+b)*2+0)*256 + t] + ws[OFF_HNC + ((1*64+b)*2+0)*256 + t]
           + ws[OFF_HG + ((0*192+p)*2+0)*256 + t] + ws[OFF_HG + ((1*192+p)*2+0)*256 + t] + dd_b1[t];
  float hs = ws[OFF_HNC + ((0*64+b)*2+1)*256 + t] + ws[OFF_HNC + ((1*64+b)*2+1)*256 + t]
           + ws[OFF_HG + ((0*192+p)*2+1)*256 + t] + ws[OFF_HG + ((1*192+p)*2+1)*256 + t] + ds_b1[t];
  __shared__ float red[256];
  __shared__ float bc[2];
  red[t] = fmaxf(hd, 0.f) * dd_w2[t];
  __syncthreads();
  for (int o=128;o>0;o>>=1){ if (t<o) red[t]+=red[t+o]; __syncthreads(); }
  if (t == 0) bc[0] = red[0] + dd_b2[0];
  __syncthreads();
  red[t] = fmaxf(hs, 0.f) * ds_w2[t];
  __syncthreads();
  for (int o=128;o>0;o>>=1){ if (t<o) red[t]+=red[t+o]; __syncthreads(); }
  if (t == 0) bc[1] = red[0] + ds_b2[0];
  __syncthreads();
  float prob  = sigmoidf_(bc[0]);
  float stren = sigmoidf_(bc[1]);
  float tvv = ws[OFF_TV + p];
  int ap = (tvv > 0.7f && tvv < 0.99f && prob > 0.5f) ? 1 : 0;
  if (t == 0){
    ((int*)(ws + OFF_APPLY))[p] = ap;
    touch_row(row, ws);
  }
  for (int d=t; d<512; d+=256){
    float n = nc[b*512 + d];
    float g = out[OUT_MEM + (size_t)row*512 + d];
    float avg = 0.5f*(n + g);
    ws[OFF_DOCAND + p*512 + d] = (1.0f - stren)*g + stren*avg;
    if (b == 0) ws[OFF_DNC0 + k*512 + d] = (1.0f - stren)*n + stren*avg;
  }
}

// ================= k_scer: scatter (blk 0..1) + erase (blk 2..129) =================
__global__ __launch_bounds__(256) void k_scer(const int* __restrict__ step_p,
    const float* __restrict__ el_w, const float* __restrict__ el_b,
    const float* __restrict__ eg_w, const float* __restrict__ eg_b,
    float* __restrict__ ws, float* __restrict__ out){
  int blk = blockIdx.x, t = threadIdx.x;
  Scal* sc = (Scal*)(ws + OFF_SCAL);
  __shared__ unsigned long long rm[256], rs[256];
  if (blk < 2){
    // ---- scatter: columns independent; batch order serialized per column ----
    int d = blk*256 + t;   // 512 columns
    const int* tip = (const int*)(ws + OFF_TI);
    const int* ap  = (const int*)(ws + OFF_APPLY);
    for (int k=0;k<3;k++){
      float cur[64];
      #pragma unroll
      for (int b=0;b<64;b++) cur[b] = out[OUT_MEM + (size_t)tip[b*3 + k]*512 + d];
      #pragma unroll
      for (int b=0;b<64;b++){
        int p = b*3 + k;
        float v = ap[p] ? ws[OFF_DOCAND + p*512 + d] : cur[b];
        out[OUT_MEM + (size_t)tip[p]*512 + d] = v;
      }
    }
    return;
  }
  // ---- erase (128 blocks) ----
  float stepf = (float)step_p[0];
  float egb = eg_b[0];
  int gid = (blk-2)*256 + t;
  int gstride = 128*256;
  unsigned long long bm = 0ULL, bs = 0ULL;
  for (int s = gid; s < S_N; s += gstride){
    float a = out[OUT_AT + s];
    float x = (stepf - a) / 1000.0f;
    float lp = 0.0f;
    #pragma unroll
    for (int j=0;j<32;j++) lp += fmaxf(x*el_w[j] + el_b[j], 0.0f) * eg_w[j];
    float er = sigmoidf_(lp + ws[OFF_CONF + s] + egb);
    float sa = stepf - a;
    bool recent = (a >= 0.0f) && (sa < 3.0f);
    float msk = recent ? 0.0f : er;
    ws[OFF_ERSC + s] = er;
    ws[OFF_MASKED + s] = msk;
    ws[OFF_SLOTAGE + s] = sa;
    unsigned long long pm = packvi(msk, s); if (pm > bm) bm = pm;
    unsigned long long ps = packvi(sa,  s); if (ps > bs) bs = ps;
  }
  rm[t]=bm; rs[t]=bs; __syncthreads();
  for (int o=128;o>0;o>>=1){
    if (t<o){ if (rm[t+o]>rm[t]) rm[t]=rm[t+o]; if (rs[t+o]>rs[t]) rs[t]=rs[t+o]; }
    __syncthreads();
  }
  if (t == 0){
    atomicMax(&sc->masked_pack, rm[0]);
    atomicMax(&sc->slotage_pack, rs[0]);
  }
}

// ================= k_finalout: decide-logic recomputed per block =================
__global__ __launch_bounds__(256) void k_finalout(const float* __restrict__ nc,
                                                  const int* __restrict__ step_p,
                                                  float* __restrict__ ws, float* __restrict__ out){
  int blk = blockIdx.x, t = threadIdx.x;
  Scal* sc = (Scal*)(ws + OFF_SCAL);
  __shared__ float red[64];
  __shared__ int sh_ss, sh_wi;
  if (t < 64) red[t] = ws[OFF_STORES + t];
  __syncthreads();
  for (int o=32;o>0;o>>=1){ if (t<o) red[t]+=red[t+o]; __syncthreads(); }
  if (t == 0){
    float store_mean = red[0] / 64.0f;
    int cnt = sc->cnt_active;
    float capacity = (float)cnt / 65536.0f;
    float dyn_thr;
    if (capacity < 0.3f) dyn_thr = 0.08f;
    else if (capacity < 0.6f) dyn_thr = 0.08f + (capacity - 0.3f)*0.733f;
    else dyn_thr = 0.3f + (capacity - 0.6f);
    dyn_thr = fminf(fmaxf(dyn_thr, 0.0f), 0.7f);
    float topk_thr = (capacity < 0.3f) ? 0.1f : ((capacity < 0.6f) ? 0.2f : 0.4f);
    float raw_thr  = (capacity < 0.3f) ? 0.3f : 0.5f;
    int base_store = store_mean > raw_thr;
    int novelty_ok = sc->nov_mean > dyn_thr;
    int cmax = cnt > 1 ? cnt : 1;
    float denom = (float)(64 * cmax);
    float perc = (cnt > 0) ? ((float)sc->cond_cnt) / denom : 1.0f;
    int topk_ok = perc > topk_thr;
    int de = sc->do_erase;
    int ss = base_store && novelty_ok && topk_ok;
    if (de && !novelty_ok) ss = 0;
    float mmax = mono2f((unsigned)(sc->masked_pack >> 32));
    int marg = (int)(0xFFFFFFFFu - (unsigned)(sc->masked_pack  & 0xFFFFFFFFULL));
    int sarg = (int)(0xFFFFFFFFu - (unsigned)(sc->slotage_pack & 0xFFFFFFFFULL));
    sh_ss = ss;
    sh_wi = de ? sc->victim_idx : ((mmax > 0.0f) ? marg : sarg);
  }
  __syncthreads();
  int ss = sh_ss, de = sc->do_erase;
  if (blk == 64){
    if (ss){
      int wi = sh_wi;
      const int* ap = (const int*)(ws + OFF_APPLY);
      for (int d=t; d<512; d+=256){
        float v = nc[d];               // b = 0 row
        if (ap[0]) v = ws[OFF_DNC0 + 0*512 + d];
        if (ap[1]) v = ws[OFF_DNC0 + 1*512 + d];
        if (ap[2]) v = ws[OFF_DNC0 + 2*512 + d];
        out[OUT_MEM + (size_t)wi*512 + d] = v;
      }
      if (t == 0){
        out[OUT_AT + wi] = (float)step_p[0];
        touch_row(wi, ws);
      }
    }
    return;
  }
  float mmax = mono2f((unsigned)(sc->masked_pack >> 32));
  bool usemask = ss && !de;
  for (int s = blk*256 + t; s < S_N; s += 64*256){
    float v;
    if (usemask) v = (mmax <= 0.0f) ? ws[OFF_SLOTAGE + s] : ws[OFF_MASKED + s];
    else v = ws[OFF_ERSC + s];
    out[OUT_ER + s] = v;
  }
}

// ================= k_diff: |out_mem - mem| over touched rows; rc folded in =================
__global__ __launch_bounds__(256) void k_diff(const float* __restrict__ mem,
                                              float* __restrict__ ws, float* __restrict__ out){
  int t = threadIdx.x;
  Scal* sc = (Scal*)(ws + OFF_SCAL);
  int cnt = sc->list_cnt;
  const int* list = (const int*)(ws + OFF_LIST);
  float lsum = 0.0f;
  for (int i = blockIdx.x; i < cnt; i += gridDim.x){
    int row = list[i];
    float part = 0.0f;
    for (int d=t; d<512; d+=256)
      part += fabsf(out[OUT_MEM + (size_t)row*512 + d] - mem[(size_t)row*512 + d]);
    lsum += part;
  }
  __shared__ float red[256];
  red[t] = lsum; __syncthreads();
  for (int o=128;o>0;o>>=1){ if (t<o) red[t]+=red[t+o]; __syncthreads(); }
  if (t == 0 && red[0] != 0.0f) atomicAdd(out + OUT_RC, red[0] * (1.0f/33554432.0f));
}

// ================= host =================
extern "C" void kernel_launch(void* const* d_in, const int* in_sizes, int n_in,
                              void* d_out, int out_size, void* d_ws, size_t ws_size,
                              hipStream_t stream) {
  const float* nc    = (const float*)d_in[0];
  const float* qr    = (const float*)d_in[1];
  const float* mem   = (const float*)d_in[2];
  const float* at    = (const float*)d_in[3];
  const int*   step  = (const int*)  d_in[4];
  const float* sr_w1 = (const float*)d_in[5];
  const float* sr_b1 = (const float*)d_in[6];
  const float* sr_g  = (const float*)d_in[7];
  const float* sr_be = (const float*)d_in[8];
  const float* sr_w2 = (const float*)d_in[9];
  const float* sr_b2 = (const float*)d_in[10];
  const float* sn_w  = (const float*)d_in[11];
  const float* sn_b  = (const float*)d_in[12];
  const float* sg_w  = (const float*)d_in[13];
  const float* sg_b  = (const float*)d_in[14];
  const float* el_w  = (const float*)d_in[15];
  const float* el_b  = (const float*)d_in[16];
  const float* ec_w  = (const float*)d_in[17];
  const float* ec_b  = (const float*)d_in[18];
  const float* eg_w  = (const float*)d_in[19];
  const float* eg_b  = (const float*)d_in[20];
  const float* dd_w1 = (const float*)d_in[21];
  const float* dd_b1 = (const float*)d_in[22];
  const float* dd_w2 = (const float*)d_in[23];
  const float* dd_b2 = (const float*)d_in[24];
  const float* ds_w1 = (const float*)d_in[25];
  const float* ds_b1 = (const float*)d_in[26];
  const float* ds_w2 = (const float*)d_in[27];
  const float* ds_b2 = (const float*)d_in[28];
  float* out = (float*)d_out;
  float* ws  = (float*)d_ws;

  k_initm    <<<dim3(1057), dim3(256), 0, stream>>>(nc, qr, at, ec_w, step, sr_w1, sn_w, ws, out);
  k_phase1   <<<dim3(256), dim3(512), 0, stream>>>(mem, ec_b, eg_w, ws, out, 0);
  k_phase1   <<<dim3(256), dim3(512), 0, stream>>>(mem, ec_b, eg_w, ws, out, 256);
  k_victim   <<<dim3(64), dim3(256), 0, stream>>>(at, step, ws);
  k_mid      <<<dim3(642), dim3(256), 0, stream>>>(nc, qr, sr_b1, sr_g, sr_be,
                                                   sr_w2, sr_b2, sn_b, sg_w, sg_b,
                                                   ec_b, eg_w, ws, out);
  k_mlp2     <<<dim3(256), dim3(256), 0, stream>>>(nc, dd_w1, ds_w1, ws, out);
  k_pairfin  <<<dim3(192), dim3(256), 0, stream>>>(nc, dd_b1, dd_w2, dd_b2,
                                                   ds_b1, ds_w2, ds_b2, ws, out);
  k_scer     <<<dim3(130), dim3(256), 0, stream>>>(step, el_w, el_b, eg_w, eg_b, ws, out);
  k_finalout <<<dim3(65), dim3(256), 0, stream>>>(nc, step, ws, out);
  k_diff     <<<dim3(64), dim3(256), 0, stream>>>(mem, ws, out);
}